// Round 4
// baseline (275.821 us; speedup 1.0000x reference)
//
#include <hip/hip_runtime.h>
#include <hip/hip_bf16.h>

// Problem constants
#define B_   16
#define N_   1024
#define C_   768
#define H_   12
#define HD_  64
#define M_   16384   // B*N tokens
#define N1_  2304    // 3*C
#define NEG_BIG (-1e30f)
#define LOG2E 1.4426950408889634f

typedef __attribute__((ext_vector_type(8))) short bf16x8;   // 8 bf16 = 4 VGPR
typedef __attribute__((ext_vector_type(4))) float f32x4;
typedef __attribute__((ext_vector_type(16))) float f32x16;

// ---- bf16 helpers via raw bits ----
__device__ __forceinline__ unsigned short f2bf(float f) {
  unsigned int u = __float_as_uint(f);
  u = u + 0x7fffu + ((u >> 16) & 1u);   // round-to-nearest-even
  return (unsigned short)(u >> 16);
}
__device__ __forceinline__ float bf2f(unsigned short h) {
  return __uint_as_float(((unsigned int)h) << 16);
}
__device__ __forceinline__ unsigned int cvtpk_bf16(float a, float b) {
  unsigned int r;
  asm("v_cvt_pk_bf16_f32 %0, %1, %2" : "=v"(r) : "v"(a), "v"(b));
  return r;  // lo16 = bf16(a), hi16 = bf16(b)
}
__device__ __forceinline__ float exp2_asm(float x) {
  float r;
  asm("v_exp_f32 %0, %1" : "=v"(r) : "v"(x));
  return r;
}

__device__ __forceinline__ void gload_lds16(const void* g, void* l) {
  __builtin_amdgcn_global_load_lds(
      (const __attribute__((address_space(1))) void*)g,
      (__attribute__((address_space(3))) void*)l, 16, 0, 0);
}

// =====================================================================
// Prep kernels
// =====================================================================

__global__ __launch_bounds__(256) void k_cvt_x(const float* __restrict__ x,
                                               unsigned short* __restrict__ xb) {
  long i = ((long)blockIdx.x * 256 + threadIdx.x) * 8;
  float4 a = *(const float4*)(x + i);
  float4 b = *(const float4*)(x + i + 4);
  bf16x8 v;
  v[0] = (short)f2bf(a.x); v[1] = (short)f2bf(a.y);
  v[2] = (short)f2bf(a.z); v[3] = (short)f2bf(a.w);
  v[4] = (short)f2bf(b.x); v[5] = (short)f2bf(b.y);
  v[6] = (short)f2bf(b.z); v[7] = (short)f2bf(b.w);
  *(bf16x8*)(xb + i) = v;
}

__global__ __launch_bounds__(256) void k_prep_wqkvT(const float* __restrict__ W,
                                                    unsigned short* __restrict__ Wt) {
  int tid = blockIdx.x * 256 + threadIdx.x;   // 96*2304 threads
  int n  = tid % N1_;
  int kc = tid / N1_;                          // 0..95
  bf16x8 v;
#pragma unroll
  for (int j = 0; j < 8; ++j)
    v[j] = (short)f2bf(W[(long)(kc * 8 + j) * N1_ + n]);
  *(bf16x8*)(Wt + (long)n * C_ + kc * 8) = v;
}

__global__ __launch_bounds__(256) void k_prep_wout(const float* __restrict__ W,
                                                   unsigned short* __restrict__ Wt3) {
  int tid = blockIdx.x * 256 + threadIdx.x;   // 96*768 threads
  int n  = tid % C_;
  int kc = tid / C_;                           // 0..95
  bf16x8 hi, lo;
#pragma unroll
  for (int j = 0; j < 8; ++j) {
    float wv = W[(long)(kc * 8 + j) * C_ + n];
    unsigned short h = f2bf(wv);
    hi[j] = (short)h;
    lo[j] = (short)f2bf(wv - bf2f(h));
  }
  unsigned short* base = Wt3 + (long)n * N1_ + kc * 8;
  *(bf16x8*)(base)        = hi;
  *(bf16x8*)(base + 768)  = hi;
  *(bf16x8*)(base + 1536) = lo;
}

// Transpose V region of qkvb into Vt [bh][64 d][1024 n] via LDS tile.
__global__ __launch_bounds__(256) void k_transposeV2(const unsigned short* __restrict__ qkvb,
                                                     unsigned short* __restrict__ Vt) {
  __shared__ unsigned char lt[16384];   // [64 d][128 n] bf16, swizzled
  int wid = (blockIdx.x & 7) * 192 + (blockIdx.x >> 3);   // XCD-chunked
  int bh = wid >> 3, nb = wid & 7;
  int b = bh / H_, h = bh % H_;
  long tok0 = (long)b * N_ + nb * 128;
  int t = threadIdx.x;
  int d0 = (t & 7) * 8;
#pragma unroll
  for (int it = 0; it < 4; ++it) {
    int nl = it * 32 + (t >> 3);
    bf16x8 v = *(const bf16x8*)(qkvb + (tok0 + nl) * N1_ + 1536 + h * HD_ + d0);
#pragma unroll
    for (int j = 0; j < 8; ++j) {
      int d = d0 + j;
      *(unsigned short*)(lt + d * 256 + ((nl * 2) ^ (((d >> 3) & 7) << 4))) =
          (unsigned short)v[j];
    }
  }
  __syncthreads();
  int l = t & 63, wv = t >> 6;
  int p = l & 1;
  int dbase = ((l >> 1) & 7) * 8 + (l >> 4) * 2;
#pragma unroll
  for (int rr = 0; rr < 4; ++rr) {
    int d = dbase + (rr & 1);
    int n0 = wv * 32 + (rr >> 1) * 16 + p * 8;
    bf16x8 v = *(const bf16x8*)(lt + d * 256 + ((n0 * 2) ^ (((d >> 3) & 7) << 4)));
    *(bf16x8*)(Vt + ((long)bh * HD_ + d) * N_ + nb * 128 + n0) = v;
  }
}

// =====================================================================
// 256x256 8-phase GEMM: C[M,N] = A[M,K](bf16) * Bt[N,K]^T(bf16) + bias
// 8 waves (2Mx4N), BK=64, 128 KiB LDS double-buffer, counted vmcnt(8),
// 2 barriers/phase, setprio around MFMA clusters (T3+T4+T5).
// STAGE 1: out bf16 qkvb (cols<768 scaled); STAGE 3: out fp32.
// =====================================================================
template <int STAGE>
__global__ __launch_bounds__(512, 2)
void gemm256(const unsigned short* __restrict__ A,
             const unsigned short* __restrict__ Bt,
             const float* __restrict__ bias,
             void* __restrict__ out, int Kdim, int Ndim) {
  extern __shared__ unsigned char lds[];   // 2 x (A 32K | B 32K) = 128 KiB
  const int t = threadIdx.x;
  const int l = t & 63, w = t >> 6;        // 8 waves
  const int g = l >> 4, lr = l & 15;
  const int wm = w >> 2, wn = w & 3;       // 2M x 4N wave grid
  const int NB = Ndim >> 8;
  const int wgid = (blockIdx.x & 7) * (gridDim.x >> 3) + (blockIdx.x >> 3);
  const int mb = wgid / NB, nb = wgid % NB;
  const long m0 = (long)mb << 8, n0 = (long)nb << 8;
  const int T = Kdim >> 6;                 // K-tiles of 64

  f32x4 acc[8][4];
  const f32x4 zz = {0.f, 0.f, 0.f, 0.f};
#pragma unroll
  for (int i = 0; i < 8; ++i)
#pragma unroll
    for (int j = 0; j < 4; ++j) acc[i][j] = zz;

  const long K2 = (long)Kdim * 2;
  const char* Ab = (const char*)A;
  const char* Bb = (const char*)Bt;
  // staging: thread slot s = i*8192 + t*16 -> row = i*64 + (t>>3), col=(t&7)*16
  // LDS linear; SOURCE pre-swizzled by ((row&7)<<4)
  const int sxcol = ((t & 7) * 16) ^ (((t >> 3) & 7) << 4);
  const int srowk = t >> 3;                // 0..63
  const int wvbase = w * 1024;             // wave-uniform LDS base

#define STAGE_T(tile, bufb)                                                  \
  {                                                                          \
    const char* As_ = Ab + (m0 + srowk) * K2 + (long)(tile) * 128 + sxcol;   \
    const char* Bs_ = Bb + (n0 + srowk) * K2 + (long)(tile) * 128 + sxcol;   \
    _Pragma("unroll")                                                        \
    for (int i = 0; i < 4; ++i)                                              \
      gload_lds16(As_ + (long)i * 64 * K2, (void*)((bufb) + i * 8192 + wvbase)); \
    _Pragma("unroll")                                                        \
    for (int i = 0; i < 4; ++i)                                              \
      gload_lds16(Bs_ + (long)i * 64 * K2, (void*)((bufb) + 32768 + i * 8192 + wvbase)); \
  }

#define READ_A(ks, base)                                                     \
  _Pragma("unroll")                                                          \
  for (int mf = 0; mf < 8; ++mf) {                                           \
    int row = wm * 128 + mf * 16 + lr;                                       \
    af[mf] = *(const bf16x8*)((base) + row * 128 +                           \
                              (((ks) * 64 + g * 16) ^ ((row & 7) << 4)));    \
  }
#define READ_B(ks, nh, base)                                                 \
  _Pragma("unroll")                                                          \
  for (int nf = 0; nf < 2; ++nf) {                                           \
    int row = wn * 64 + (nh) * 32 + nf * 16 + lr;                            \
    bfr[nf] = *(const bf16x8*)((base) + 32768 + row * 128 +                  \
                               (((ks) * 64 + g * 16) ^ ((row & 7) << 4)));   \
  }
#define MFMA16(nh)                                                           \
  _Pragma("unroll")                                                          \
  for (int mf = 0; mf < 8; ++mf) {                                           \
    acc[mf][(nh) * 2 + 0] = __builtin_amdgcn_mfma_f32_16x16x32_bf16(         \
        af[mf], bfr[0], acc[mf][(nh) * 2 + 0], 0, 0, 0);                     \
    acc[mf][(nh) * 2 + 1] = __builtin_amdgcn_mfma_f32_16x16x32_bf16(         \
        af[mf], bfr[1], acc[mf][(nh) * 2 + 1], 0, 0, 0);                     \
  }

  // prologue: stage tiles 0,1; wait tile0; barrier
  STAGE_T(0, lds);
  STAGE_T(1, lds + 65536);
  asm volatile("s_waitcnt vmcnt(8)" ::: "memory");
  __builtin_amdgcn_s_barrier();
  __builtin_amdgcn_sched_barrier(0);

  for (int tt = 0; tt < T; ++tt) {
    unsigned char* base = lds + (tt & 1) * 65536;
    bf16x8 af[8], bfr[2];
    // ---- phase 1: (ks0, nh0) ----
    READ_A(0, base);
    READ_B(0, 0, base);
    __builtin_amdgcn_s_barrier();
    __builtin_amdgcn_sched_barrier(0);
    __builtin_amdgcn_s_setprio(1);
    MFMA16(0);
    __builtin_amdgcn_s_setprio(0);
    __builtin_amdgcn_sched_barrier(0);
    __builtin_amdgcn_s_barrier();
    // ---- phase 2: (ks0, nh1) ----
    READ_B(0, 1, base);
    __builtin_amdgcn_s_barrier();
    __builtin_amdgcn_sched_barrier(0);
    __builtin_amdgcn_s_setprio(1);
    MFMA16(1);
    __builtin_amdgcn_s_setprio(0);
    __builtin_amdgcn_sched_barrier(0);
    __builtin_amdgcn_s_barrier();
    // ---- phase 3: (ks1, nh0) ----
    READ_A(1, base);
    READ_B(1, 0, base);
    __builtin_amdgcn_s_barrier();
    __builtin_amdgcn_sched_barrier(0);
    __builtin_amdgcn_s_setprio(1);
    MFMA16(0);
    __builtin_amdgcn_s_setprio(0);
    __builtin_amdgcn_sched_barrier(0);
    __builtin_amdgcn_s_barrier();
    // ---- phase 4: (ks1, nh1) + stage tile tt+2 + counted vmcnt ----
    READ_B(1, 1, base);
    __builtin_amdgcn_s_barrier();     // all waves done reading buf[tt&1]
    __builtin_amdgcn_sched_barrier(0);
    if (tt + 2 < T) {
      STAGE_T(tt + 2, base);          // same-parity buffer, now dead
      asm volatile("s_waitcnt vmcnt(8)" ::: "memory");  // tile tt+1 landed
    } else if (tt + 1 < T) {
      asm volatile("s_waitcnt vmcnt(0)" ::: "memory");
    }
    __builtin_amdgcn_s_setprio(1);
    MFMA16(1);
    __builtin_amdgcn_s_setprio(0);
    __builtin_amdgcn_sched_barrier(0);
    __builtin_amdgcn_s_barrier();
  }
#undef STAGE_T
#undef READ_A
#undef READ_B
#undef MFMA16

  // epilogue: D-frag col = lane&15, row = (lane>>4)*4 + r
#pragma unroll
  for (int j = 0; j < 4; ++j) {
    int col = (int)n0 + wn * 64 + (j >> 1) * 32 + (j & 1) * 16 + lr;
    float bv = bias[col];
    if (STAGE == 1) {
      // pre-scale Q by (1/sqrt(HD)) * log2(e)  -> softmax runs in exp2 domain
      float sc = (col < 768) ? 0.125f * LOG2E : 1.0f;
      unsigned short* o = (unsigned short*)out;
#pragma unroll
      for (int mf = 0; mf < 8; ++mf)
#pragma unroll
        for (int r = 0; r < 4; ++r) {
          long rowm = m0 + wm * 128 + mf * 16 + g * 4 + r;
          o[rowm * N1_ + col] = f2bf((acc[mf][j][r] + bv) * sc);
        }
    } else {
      float* o = (float*)out;
#pragma unroll
      for (int mf = 0; mf < 8; ++mf)
#pragma unroll
        for (int r = 0; r < 4; ++r) {
          long rowm = m0 + wm * 128 + mf * 16 + g * 4 + r;
          o[rowm * C_ + col] = acc[mf][j][r] + bv;
        }
    }
  }
}

// =====================================================================
// Fused flash attention, 32x32x16 MFMA, fully-transposed form.
// K/V LDS swizzle: period-4 / 32B  (byte ^= (row&3)<<5) to match the
// 32-row x 32B read pattern of the 32x32 fragments.
// =====================================================================
__global__ __launch_bounds__(256, 3)
void attn_fused(const unsigned short* __restrict__ qkvb,
                const unsigned short* __restrict__ Vt,
                unsigned short* __restrict__ Osp) {
  __shared__ unsigned char lds[32768];  // 2 x (K 8K | V 8K)
  const int t = threadIdx.x, l = t & 63, w = t >> 6;
  const int q32 = l & 31;              // lane's q within wave block
  const int hi = l >> 5;               // lane half
  const int hi16 = hi * 16;            // byte offset of k-subblock in LDS reads
  // XCD-chunked swizzle: 8 q-blocks of one head share one XCD's L2
  const int wid = (blockIdx.x & 7) * 192 + (blockIdx.x >> 3);
  const int bh = wid >> 3, qb = wid & 7;
  const int b = bh / H_, h = bh % H_;
  const long tok0 = (long)b * N_;
  const int q0 = qb * 128 + w * 32;
  const long mytok = tok0 + q0 + q32;

  // Q B-fragments: lane (q, hi) holds c = cs*16 + hi*8 + j  (pre-scaled)
  bf16x8 qa[4];
#pragma unroll
  for (int cs = 0; cs < 4; ++cs)
    qa[cs] = *(const bf16x8*)(qkvb + mytok * N1_ + h * HD_ + cs * 16 + hi * 8);

  const f32x16 zz16 = {0.f};
  f32x16 o0 = zz16, o1 = zz16;   // O^T: d 0..31 / 32..63 for lane's q
  float mrun = NEG_BIG, lrun = 0.f;

  const int row0 = q32, row1 = 32 + q32;
  const int swz0 = (q32 & 3) << 5;    // period-4 / 32B XOR

  // staging decode (slot = t*16 in 4K subtile; row=(i*32)+(t>>3), col=(t&7)*16)
  const int sxs = ((t & 7) * 16) ^ (((t >> 3) & 3) << 5);
  const int wbase = (t & 192) * 16;
  const char* Vg = (const char*)(Vt + (long)bh * HD_ * N_);
  const char* Kg = (const char*)qkvb + ((tok0)*N1_ + C_ + h * HD_) * 2;

#define STAGE_KV(kv0, buf)                                                  \
  {                                                                         \
    _Pragma("unroll")                                                       \
    for (int i = 0; i < 2; ++i) {                                           \
      int row = i * 32 + (t >> 3);                                          \
      gload_lds16(Kg + ((long)(kv0 + row) * N1_) * 2 + sxs,                 \
                  (void*)((buf) + i * 4096 + wbase));                       \
    }                                                                       \
    _Pragma("unroll")                                                       \
    for (int i = 0; i < 2; ++i) {                                           \
      int row = i * 32 + (t >> 3);                                          \
      gload_lds16(Vg + ((long)row * N_ + (kv0)) * 2 + sxs,                  \
                  (void*)((buf) + 8192 + i * 4096 + wbase));                \
    }                                                                       \
  }

  STAGE_KV(0, lds);

#pragma unroll 2
  for (int tt = 0; tt < 16; ++tt) {
    unsigned char* curb = lds + (tt & 1) * 16384;
    unsigned char* nxtb = lds + ((tt & 1) ^ 1) * 16384;
    if (tt < 15) {
      STAGE_KV((tt + 1) * 64, nxtb);
      asm volatile("s_waitcnt vmcnt(4)" ::: "memory");
    } else {
      asm volatile("s_waitcnt vmcnt(0)" ::: "memory");
    }
    __builtin_amdgcn_s_barrier();
    __builtin_amdgcn_sched_barrier(0);

    // ---- S^T = mfma(K_A, Q_B): two 32-k tiles ----
    f32x16 sa0 = zz16, sa1 = zz16;
#pragma unroll
    for (int cs = 0; cs < 4; ++cs) {
      bf16x8 kf0 = *(const bf16x8*)(curb + row0 * 128 + ((cs * 32 + hi16) ^ swz0));
      bf16x8 kf1 = *(const bf16x8*)(curb + row1 * 128 + ((cs * 32 + hi16) ^ swz0));
      sa0 = __builtin_amdgcn_mfma_f32_32x32x16_bf16(kf0, qa[cs], sa0, 0, 0, 0);
      sa1 = __builtin_amdgcn_mfma_f32_32x32x16_bf16(kf1, qa[cs], sa1, 0, 0, 0);
    }

    // ---- in-lane online softmax (log2 domain) ----
    float mx = sa0[0];
#pragma unroll
    for (int r = 1; r < 16; ++r) mx = fmaxf(mx, sa0[r]);
#pragma unroll
    for (int r = 0; r < 16; ++r) mx = fmaxf(mx, sa1[r]);
    mx = fmaxf(mx, __shfl_xor(mx, 32));
    if (!__all(mx <= mrun + 8.f)) {           // defer-max: rescale only on growth
      float mn = fmaxf(mrun, mx);
      float al = exp2_asm(mrun - mn);
      mrun = mn;
      lrun *= al;
      o0 *= al;
      o1 *= al;
    }
    float rs = 0.f;
    unsigned pk[2][4][2];
#pragma unroll
    for (int g = 0; g < 4; ++g) {
      float p0 = exp2_asm(sa0[4 * g + 0] - mrun);
      float p1 = exp2_asm(sa0[4 * g + 1] - mrun);
      float p2 = exp2_asm(sa0[4 * g + 2] - mrun);
      float p3 = exp2_asm(sa0[4 * g + 3] - mrun);
      rs += (p0 + p1) + (p2 + p3);
      pk[0][g][0] = cvtpk_bf16(p0, p1);
      pk[0][g][1] = cvtpk_bf16(p2, p3);
    }
#pragma unroll
    for (int g = 0; g < 4; ++g) {
      float p0 = exp2_asm(sa1[4 * g + 0] - mrun);
      float p1 = exp2_asm(sa1[4 * g + 1] - mrun);
      float p2 = exp2_asm(sa1[4 * g + 2] - mrun);
      float p3 = exp2_asm(sa1[4 * g + 3] - mrun);
      rs += (p0 + p1) + (p2 + p3);
      pk[1][g][0] = cvtpk_bf16(p0, p1);
      pk[1][g][1] = cvtpk_bf16(p2, p3);
    }
    rs += __shfl_xor(rs, 32);
    lrun += rs;

    // ---- P^T -> B-operand fragments via permlane32_swap ----
    bf16x8 pb[4];
#pragma unroll
    for (int tk = 0; tk < 2; ++tk)
#pragma unroll
      for (int par = 0; par < 2; ++par) {
        unsigned a0 = pk[tk][2 * par][0], b0 = pk[tk][2 * par + 1][0];
        unsigned a1 = pk[tk][2 * par][1], b1 = pk[tk][2 * par + 1][1];
        asm("v_permlane32_swap_b32 %0, %1" : "+v"(a0), "+v"(b0));
        asm("v_permlane32_swap_b32 %0, %1" : "+v"(a1), "+v"(b1));
        union { unsigned u[4]; bf16x8 v; } pw;
        pw.u[0] = a0; pw.u[1] = a1; pw.u[2] = b0; pw.u[3] = b1;
        pb[2 * tk + par] = pw.v;
      }

    // ---- O^T += mfma(V^T_A, P_B) ----
#pragma unroll
    for (int kb = 0; kb < 4; ++kb) {
      bf16x8 vf0 = *(const bf16x8*)(curb + 8192 + row0 * 128 + ((kb * 32 + hi16) ^ swz0));
      bf16x8 vf1 = *(const bf16x8*)(curb + 8192 + row1 * 128 + ((kb * 32 + hi16) ^ swz0));
      o0 = __builtin_amdgcn_mfma_f32_32x32x16_bf16(vf0, pb[kb], o0, 0, 0, 0);
      o1 = __builtin_amdgcn_mfma_f32_32x32x16_bf16(vf1, pb[kb], o1, 0, 0, 0);
    }
    __builtin_amdgcn_sched_barrier(0);
    asm volatile("s_waitcnt lgkmcnt(0)" ::: "memory");
    __builtin_amdgcn_s_barrier();
  }
#undef STAGE_KV

  // ---- epilogue: normalize lane's own q-row, split hi/lo, paired stores ----
  float inv = 1.0f / lrun;
  unsigned short* obase = Osp + mytok * N1_ + h * HD_;
#pragma unroll
  for (int dt = 0; dt < 2; ++dt) {
#pragma unroll
    for (int rp = 0; rp < 8; ++rp) {
      int r = rp * 2;
      float v0 = (dt ? o1[r] : o0[r]) * inv;
      float v1 = (dt ? o1[r + 1] : o0[r + 1]) * inv;
      unsigned hw = cvtpk_bf16(v0, v1);
      float l0 = v0 - bf2f((unsigned short)(hw & 0xffff));
      float l1 = v1 - bf2f((unsigned short)(hw >> 16));
      unsigned lw = cvtpk_bf16(l0, l1);
      int d = dt * 32 + (r & 3) + 8 * (r >> 2) + 4 * hi;
      *(unsigned*)(obase + d) = hw;
      *(unsigned*)(obase + 768 + d) = lw;
      *(unsigned*)(obase + 1536 + d) = hw;
    }
  }
}

// =====================================================================
extern "C" void kernel_launch(void* const* d_in, const int* in_sizes, int n_in,
                              void* d_out, int out_size, void* d_ws, size_t ws_size,
                              hipStream_t stream) {
  const float* x    = (const float*)d_in[0];
  const float* Wqkv = (const float*)d_in[1];
  const float* bqkv = (const float*)d_in[2];
  const float* Wout = (const float*)d_in[3];
  const float* bout = (const float*)d_in[4];

  char* ws = (char*)d_ws;
  unsigned short* qkvb  = (unsigned short*)(ws);                 // 75,497,472 B
  unsigned short* Osp   = (unsigned short*)(ws + 75497472L);     // 75,497,472 B
  unsigned short* xb    = (unsigned short*)(ws + 150994944L);    // 25,165,824 B
  unsigned short* Vt    = (unsigned short*)(ws + 150994944L);    // alias of xb
  unsigned short* WqkvT = (unsigned short*)(ws + 176160768L);    //  3,538,944 B
  unsigned short* Wt3   = (unsigned short*)(ws + 179699712L);    //  3,538,944 B

  // 128 KiB dynamic LDS opt-in for the 256^2 GEMMs
  hipFuncSetAttribute((const void*)gemm256<1>,
                      hipFuncAttributeMaxDynamicSharedMemorySize, 131072);
  hipFuncSetAttribute((const void*)gemm256<3>,
                      hipFuncAttributeMaxDynamicSharedMemorySize, 131072);

  k_cvt_x<<<6144, 256, 0, stream>>>(x, xb);
  k_prep_wqkvT<<<864, 256, 0, stream>>>(Wqkv, WqkvT);
  k_prep_wout<<<288, 256, 0, stream>>>(Wout, Wt3);
  gemm256<1><<<576, 512, 131072, stream>>>(xb, WqkvT, bqkv, (void*)qkvb, 768, 2304);
  k_transposeV2<<<1536, 256, 0, stream>>>(qkvb, Vt);
  attn_fused<<<1536, 256, 0, stream>>>(qkvb, Vt, Osp);
  gemm256<3><<<192, 512, 131072, stream>>>(Osp, Wt3, bout, d_out, 2304, 768);
}

// Round 5
// 262.650 us; speedup vs baseline: 1.0501x; 1.0501x over previous
//
#include <hip/hip_runtime.h>
#include <hip/hip_bf16.h>

// Problem constants
#define B_   16
#define N_   1024
#define C_   768
#define H_   12
#define HD_  64
#define M_   16384   // B*N tokens
#define N1_  2304    // 3*C
#define NEG_BIG (-1e30f)
#define LOG2E 1.4426950408889634f

typedef __attribute__((ext_vector_type(8))) short bf16x8;   // 8 bf16 = 4 VGPR
typedef __attribute__((ext_vector_type(4))) float f32x4;
typedef __attribute__((ext_vector_type(16))) float f32x16;

// ---- bf16 helpers via raw bits ----
__device__ __forceinline__ unsigned short f2bf(float f) {
  unsigned int u = __float_as_uint(f);
  u = u + 0x7fffu + ((u >> 16) & 1u);   // round-to-nearest-even
  return (unsigned short)(u >> 16);
}
__device__ __forceinline__ float bf2f(unsigned short h) {
  return __uint_as_float(((unsigned int)h) << 16);
}
__device__ __forceinline__ unsigned int cvtpk_bf16(float a, float b) {
  unsigned int r;
  asm("v_cvt_pk_bf16_f32 %0, %1, %2" : "=v"(r) : "v"(a), "v"(b));
  return r;  // lo16 = bf16(a), hi16 = bf16(b)
}
__device__ __forceinline__ float exp2_asm(float x) {
  float r;
  asm("v_exp_f32 %0, %1" : "=v"(r) : "v"(x));
  return r;
}

__device__ __forceinline__ void gload_lds16(const void* g, void* l) {
  __builtin_amdgcn_global_load_lds(
      (const __attribute__((address_space(1))) void*)g,
      (__attribute__((address_space(3))) void*)l, 16, 0, 0);
}

// =====================================================================
// Prep kernels
// =====================================================================

__global__ __launch_bounds__(256) void k_cvt_x(const float* __restrict__ x,
                                               unsigned short* __restrict__ xb) {
  long i = ((long)blockIdx.x * 256 + threadIdx.x) * 8;
  float4 a = *(const float4*)(x + i);
  float4 b = *(const float4*)(x + i + 4);
  bf16x8 v;
  v[0] = (short)f2bf(a.x); v[1] = (short)f2bf(a.y);
  v[2] = (short)f2bf(a.z); v[3] = (short)f2bf(a.w);
  v[4] = (short)f2bf(b.x); v[5] = (short)f2bf(b.y);
  v[6] = (short)f2bf(b.z); v[7] = (short)f2bf(b.w);
  *(bf16x8*)(xb + i) = v;
}

__global__ __launch_bounds__(256) void k_prep_wqkvT(const float* __restrict__ W,
                                                    unsigned short* __restrict__ Wt) {
  int tid = blockIdx.x * 256 + threadIdx.x;   // 96*2304 threads
  int n  = tid % N1_;
  int kc = tid / N1_;                          // 0..95
  bf16x8 v;
#pragma unroll
  for (int j = 0; j < 8; ++j)
    v[j] = (short)f2bf(W[(long)(kc * 8 + j) * N1_ + n]);
  *(bf16x8*)(Wt + (long)n * C_ + kc * 8) = v;
}

__global__ __launch_bounds__(256) void k_prep_wout(const float* __restrict__ W,
                                                   unsigned short* __restrict__ Wt3) {
  int tid = blockIdx.x * 256 + threadIdx.x;   // 96*768 threads
  int n  = tid % C_;
  int kc = tid / C_;                           // 0..95
  bf16x8 hi, lo;
#pragma unroll
  for (int j = 0; j < 8; ++j) {
    float wv = W[(long)(kc * 8 + j) * C_ + n];
    unsigned short h = f2bf(wv);
    hi[j] = (short)h;
    lo[j] = (short)f2bf(wv - bf2f(h));
  }
  unsigned short* base = Wt3 + (long)n * N1_ + kc * 8;
  *(bf16x8*)(base)        = hi;
  *(bf16x8*)(base + 768)  = hi;
  *(bf16x8*)(base + 1536) = lo;
}

// Transpose V region of qkvb into Vt [bh][64 d][1024 n] via LDS tile.
__global__ __launch_bounds__(256) void k_transposeV2(const unsigned short* __restrict__ qkvb,
                                                     unsigned short* __restrict__ Vt) {
  __shared__ unsigned char lt[16384];   // [64 d][128 n] bf16, swizzled
  int wid = (blockIdx.x & 7) * 192 + (blockIdx.x >> 3);   // XCD-chunked
  int bh = wid >> 3, nb = wid & 7;
  int b = bh / H_, h = bh % H_;
  long tok0 = (long)b * N_ + nb * 128;
  int t = threadIdx.x;
  int d0 = (t & 7) * 8;
#pragma unroll
  for (int it = 0; it < 4; ++it) {
    int nl = it * 32 + (t >> 3);
    bf16x8 v = *(const bf16x8*)(qkvb + (tok0 + nl) * N1_ + 1536 + h * HD_ + d0);
#pragma unroll
    for (int j = 0; j < 8; ++j) {
      int d = d0 + j;
      *(unsigned short*)(lt + d * 256 + ((nl * 2) ^ (((d >> 3) & 7) << 4))) =
          (unsigned short)v[j];
    }
  }
  __syncthreads();
  int l = t & 63, wv = t >> 6;
  int p = l & 1;
  int dbase = ((l >> 1) & 7) * 8 + (l >> 4) * 2;
#pragma unroll
  for (int rr = 0; rr < 4; ++rr) {
    int d = dbase + (rr & 1);
    int n0 = wv * 32 + (rr >> 1) * 16 + p * 8;
    bf16x8 v = *(const bf16x8*)(lt + d * 256 + ((n0 * 2) ^ (((d >> 3) & 7) << 4)));
    *(bf16x8*)(Vt + ((long)bh * HD_ + d) * N_ + nb * 128 + n0) = v;
  }
}

// =====================================================================
// 256x256 8-phase GEMM (template-faithful port): 8 waves (2Mx4N), BK=64,
// 128 KiB LDS dbuf. Staging SPREAD 2 loads/phase; ONE counted vmcnt per
// K-tile at end of ph4, before its barrier. No sched_barrier. T3+T4+T5.
// STAGE 1: out bf16 qkvb via LDS-coalesced epilogue; STAGE 3: out fp32.
// =====================================================================
template <int STAGE>
__global__ __launch_bounds__(512, 2)
void gemm256(const unsigned short* __restrict__ A,
             const unsigned short* __restrict__ Bt,
             const float* __restrict__ bias,
             void* __restrict__ out, int Kdim, int Ndim) {
  extern __shared__ unsigned char lds[];   // 2 x (A 32K | B 32K) = 128 KiB
  const int t = threadIdx.x;
  const int l = t & 63, w = t >> 6;        // 8 waves
  const int g = l >> 4, lr = l & 15;
  const int wm = w >> 2, wn = w & 3;       // 2M x 4N wave grid
  const int NB = Ndim >> 8;
  const int wgid = (blockIdx.x & 7) * (gridDim.x >> 3) + (blockIdx.x >> 3);
  const int mb = wgid / NB, nb = wgid % NB;
  const long m0 = (long)mb << 8, n0 = (long)nb << 8;
  const int T = Kdim >> 6;                 // K-tiles of 64

  f32x4 acc[8][4];
  const f32x4 zz = {0.f, 0.f, 0.f, 0.f};
#pragma unroll
  for (int i = 0; i < 8; ++i)
#pragma unroll
    for (int j = 0; j < 4; ++j) acc[i][j] = zz;

  const long K2 = (long)Kdim * 2;
  const char* Ab = (const char*)A;
  const char* Bb = (const char*)Bt;
  // staging: load i covers rows i*64+(t>>3), col (t&7)*16 (src pre-swizzled);
  // LDS dest linear: i*8192 + wave_base (+lane*16 implicit)
  const int sxcol = ((t & 7) * 16) ^ (((t >> 3) & 7) << 4);
  const int srowk = t >> 3;                // 0..63
  const int wvbase = w * 1024;

#define STAGE_A2(tile, i0)                                                   \
  {                                                                          \
    unsigned char* bufb_ = lds + ((tile) & 1) * 65536;                       \
    const char* As_ = Ab + (m0 + srowk) * K2 + (long)(tile) * 128 + sxcol;   \
    gload_lds16(As_ + (long)((i0) * 64) * K2,                                \
                (void*)(bufb_ + (i0) * 8192 + wvbase));                      \
    gload_lds16(As_ + (long)(((i0) + 1) * 64) * K2,                          \
                (void*)(bufb_ + ((i0) + 1) * 8192 + wvbase));                \
  }
#define STAGE_B2(tile, i0)                                                   \
  {                                                                          \
    unsigned char* bufb_ = lds + ((tile) & 1) * 65536 + 32768;               \
    const char* Bs_ = Bb + (n0 + srowk) * K2 + (long)(tile) * 128 + sxcol;   \
    gload_lds16(Bs_ + (long)((i0) * 64) * K2,                                \
                (void*)(bufb_ + (i0) * 8192 + wvbase));                      \
    gload_lds16(Bs_ + (long)(((i0) + 1) * 64) * K2,                          \
                (void*)(bufb_ + ((i0) + 1) * 8192 + wvbase));                \
  }

#define READ_A(ks, base)                                                     \
  _Pragma("unroll")                                                          \
  for (int mf = 0; mf < 8; ++mf) {                                           \
    int row = wm * 128 + mf * 16 + lr;                                       \
    af[mf] = *(const bf16x8*)((base) + row * 128 +                           \
                              (((ks) * 64 + g * 16) ^ ((row & 7) << 4)));    \
  }
#define READ_B(ks, nh, base)                                                 \
  _Pragma("unroll")                                                          \
  for (int nf = 0; nf < 2; ++nf) {                                           \
    int row = wn * 64 + (nh) * 32 + nf * 16 + lr;                            \
    bfr[nf] = *(const bf16x8*)((base) + 32768 + row * 128 +                  \
                               (((ks) * 64 + g * 16) ^ ((row & 7) << 4)));   \
  }
#define MFMA16(nh)                                                           \
  _Pragma("unroll")                                                          \
  for (int mf = 0; mf < 8; ++mf) {                                           \
    acc[mf][(nh) * 2 + 0] = __builtin_amdgcn_mfma_f32_16x16x32_bf16(         \
        af[mf], bfr[0], acc[mf][(nh) * 2 + 0], 0, 0, 0);                     \
    acc[mf][(nh) * 2 + 1] = __builtin_amdgcn_mfma_f32_16x16x32_bf16(         \
        af[mf], bfr[1], acc[mf][(nh) * 2 + 1], 0, 0, 0);                     \
  }
#define BAR()  __builtin_amdgcn_s_barrier(); asm volatile("" ::: "memory")

  // prologue: fully stage tiles 0 and 1 (16 loads); wait tile-0 set
  STAGE_A2(0, 0); STAGE_A2(0, 2); STAGE_B2(0, 0); STAGE_B2(0, 2);
  STAGE_A2(1, 0); STAGE_A2(1, 2); STAGE_B2(1, 0); STAGE_B2(1, 2);
  asm volatile("s_waitcnt vmcnt(8)" ::: "memory");
  BAR();

  for (int tt = 0; tt < T; ++tt) {
    unsigned char* base = lds + (tt & 1) * 65536;
    bf16x8 af[8], bfr[2];
    // ---- ph1: read A.ks0 + B.ks0.nh0 ; stage B(t+1)[0:2] ----
    READ_A(0, base);
    READ_B(0, 0, base);
    if (tt >= 1 && tt + 1 < T) STAGE_B2(tt + 1, 0);
    BAR();
    __builtin_amdgcn_s_setprio(1);
    MFMA16(0);
    __builtin_amdgcn_s_setprio(0);
    BAR();
    // ---- ph2: read B.ks0.nh1 ; stage B(t+1)[2:4] ----
    READ_B(0, 1, base);
    if (tt >= 1 && tt + 1 < T) STAGE_B2(tt + 1, 2);
    BAR();
    __builtin_amdgcn_s_setprio(1);
    MFMA16(1);
    __builtin_amdgcn_s_setprio(0);
    BAR();
    // ---- ph3: read A.ks1 + B.ks1.nh0 ; stage A(t+1)[2:4] ----
    READ_A(1, base);
    READ_B(1, 0, base);
    if (tt >= 1 && tt + 1 < T) STAGE_A2(tt + 1, 2);
    BAR();
    __builtin_amdgcn_s_setprio(1);
    MFMA16(0);
    __builtin_amdgcn_s_setprio(0);
    BAR();
    // ---- ph4: read B.ks1.nh1 ; stage A(t+2)[0:2] ; counted vmcnt ----
    READ_B(1, 1, base);
    if (tt + 2 < T) STAGE_A2(tt + 2, 0);   // same-parity A-buf: reads done at ph3
    BAR();
    __builtin_amdgcn_s_setprio(1);
    MFMA16(1);
    __builtin_amdgcn_s_setprio(0);
    if (tt + 1 < T) {
      if (tt + 2 < T) { asm volatile("s_waitcnt vmcnt(2)" ::: "memory"); }
      else            { asm volatile("s_waitcnt vmcnt(0)" ::: "memory"); }
    }
    BAR();
  }
#undef STAGE_A2
#undef STAGE_B2
#undef READ_A
#undef READ_B
#undef MFMA16

  // ---- epilogue ----
  if (STAGE == 1) {
    // stage C-tile (256x256 bf16 = 128 KiB) in LDS, then coalesced stores
    float sc = (n0 < 768) ? 0.125f * LOG2E : 1.0f;  // block cols uniform
    unsigned short* cl = (unsigned short*)lds;
#pragma unroll
    for (int j = 0; j < 4; ++j) {
      int col = wn * 64 + (j >> 1) * 32 + (j & 1) * 16 + lr;
      float bv = bias[(int)n0 + col];
#pragma unroll
      for (int mf = 0; mf < 8; ++mf)
#pragma unroll
        for (int r = 0; r < 4; ++r) {
          int row = wm * 128 + mf * 16 + g * 4 + r;
          cl[row * 256 + col] = f2bf((acc[mf][j][r] + bv) * sc);
        }
    }
    __syncthreads();
    unsigned short* o = (unsigned short*)out;
#pragma unroll
    for (int it = 0; it < 16; ++it) {
      int idx = it * 4096 + t * 8;         // shorts
      int row = idx >> 8;
      int col = idx & 255;
      *(bf16x8*)(o + (m0 + row) * N1_ + n0 + col) = *(const bf16x8*)(cl + idx);
    }
  } else {
    float* o = (float*)out;
#pragma unroll
    for (int j = 0; j < 4; ++j) {
      int col = (int)n0 + wn * 64 + (j >> 1) * 32 + (j & 1) * 16 + lr;
      float bv = bias[col];
#pragma unroll
      for (int mf = 0; mf < 8; ++mf)
#pragma unroll
        for (int r = 0; r < 4; ++r) {
          long rowm = m0 + wm * 128 + mf * 16 + g * 4 + r;
          o[rowm * C_ + col] = acc[mf][j][r] + bv;
        }
    }
  }
#undef BAR
}

// =====================================================================
// Fused flash attention, 32x32x16 MFMA, fully-transposed form (unchanged).
// =====================================================================
__global__ __launch_bounds__(256, 3)
void attn_fused(const unsigned short* __restrict__ qkvb,
                const unsigned short* __restrict__ Vt,
                unsigned short* __restrict__ Osp) {
  __shared__ unsigned char lds[32768];  // 2 x (K 8K | V 8K)
  const int t = threadIdx.x, l = t & 63, w = t >> 6;
  const int q32 = l & 31;              // lane's q within wave block
  const int hi = l >> 5;               // lane half
  const int hi16 = hi * 16;            // byte offset of k-subblock in LDS reads
  // XCD-chunked swizzle: 8 q-blocks of one head share one XCD's L2
  const int wid = (blockIdx.x & 7) * 192 + (blockIdx.x >> 3);
  const int bh = wid >> 3, qb = wid & 7;
  const int b = bh / H_, h = bh % H_;
  const long tok0 = (long)b * N_;
  const int q0 = qb * 128 + w * 32;
  const long mytok = tok0 + q0 + q32;

  // Q B-fragments: lane (q, hi) holds c = cs*16 + hi*8 + j  (pre-scaled)
  bf16x8 qa[4];
#pragma unroll
  for (int cs = 0; cs < 4; ++cs)
    qa[cs] = *(const bf16x8*)(qkvb + mytok * N1_ + h * HD_ + cs * 16 + hi * 8);

  const f32x16 zz16 = {0.f};
  f32x16 o0 = zz16, o1 = zz16;   // O^T: d 0..31 / 32..63 for lane's q
  float mrun = NEG_BIG, lrun = 0.f;

  const int row0 = q32, row1 = 32 + q32;
  const int swz0 = (q32 & 3) << 5;    // period-4 / 32B XOR

  // staging decode (slot = t*16 in 4K subtile; row=(i*32)+(t>>3), col=(t&7)*16)
  const int sxs = ((t & 7) * 16) ^ (((t >> 3) & 3) << 5);
  const int wbase = (t & 192) * 16;
  const char* Vg = (const char*)(Vt + (long)bh * HD_ * N_);
  const char* Kg = (const char*)qkvb + ((tok0)*N1_ + C_ + h * HD_) * 2;

#define STAGE_KV(kv0, buf)                                                  \
  {                                                                         \
    _Pragma("unroll")                                                       \
    for (int i = 0; i < 2; ++i) {                                           \
      int row = i * 32 + (t >> 3);                                          \
      gload_lds16(Kg + ((long)(kv0 + row) * N1_) * 2 + sxs,                 \
                  (void*)((buf) + i * 4096 + wbase));                       \
    }                                                                       \
    _Pragma("unroll")                                                       \
    for (int i = 0; i < 2; ++i) {                                           \
      int row = i * 32 + (t >> 3);                                          \
      gload_lds16(Vg + ((long)row * N_ + (kv0)) * 2 + sxs,                  \
                  (void*)((buf) + 8192 + i * 4096 + wbase));                \
    }                                                                       \
  }

  STAGE_KV(0, lds);

#pragma unroll 2
  for (int tt = 0; tt < 16; ++tt) {
    unsigned char* curb = lds + (tt & 1) * 16384;
    unsigned char* nxtb = lds + ((tt & 1) ^ 1) * 16384;
    if (tt < 15) {
      STAGE_KV((tt + 1) * 64, nxtb);
      asm volatile("s_waitcnt vmcnt(4)" ::: "memory");
    } else {
      asm volatile("s_waitcnt vmcnt(0)" ::: "memory");
    }
    __builtin_amdgcn_s_barrier();
    __builtin_amdgcn_sched_barrier(0);

    // ---- S^T = mfma(K_A, Q_B): two 32-k tiles ----
    f32x16 sa0 = zz16, sa1 = zz16;
#pragma unroll
    for (int cs = 0; cs < 4; ++cs) {
      bf16x8 kf0 = *(const bf16x8*)(curb + row0 * 128 + ((cs * 32 + hi16) ^ swz0));
      bf16x8 kf1 = *(const bf16x8*)(curb + row1 * 128 + ((cs * 32 + hi16) ^ swz0));
      sa0 = __builtin_amdgcn_mfma_f32_32x32x16_bf16(kf0, qa[cs], sa0, 0, 0, 0);
      sa1 = __builtin_amdgcn_mfma_f32_32x32x16_bf16(kf1, qa[cs], sa1, 0, 0, 0);
    }

    // ---- in-lane online softmax (log2 domain) ----
    float mx = sa0[0];
#pragma unroll
    for (int r = 1; r < 16; ++r) mx = fmaxf(mx, sa0[r]);
#pragma unroll
    for (int r = 0; r < 16; ++r) mx = fmaxf(mx, sa1[r]);
    mx = fmaxf(mx, __shfl_xor(mx, 32));
    if (!__all(mx <= mrun + 8.f)) {           // defer-max: rescale only on growth
      float mn = fmaxf(mrun, mx);
      float al = exp2_asm(mrun - mn);
      mrun = mn;
      lrun *= al;
      o0 *= al;
      o1 *= al;
    }
    float rs = 0.f;
    unsigned pk[2][4][2];
#pragma unroll
    for (int g = 0; g < 4; ++g) {
      float p0 = exp2_asm(sa0[4 * g + 0] - mrun);
      float p1 = exp2_asm(sa0[4 * g + 1] - mrun);
      float p2 = exp2_asm(sa0[4 * g + 2] - mrun);
      float p3 = exp2_asm(sa0[4 * g + 3] - mrun);
      rs += (p0 + p1) + (p2 + p3);
      pk[0][g][0] = cvtpk_bf16(p0, p1);
      pk[0][g][1] = cvtpk_bf16(p2, p3);
    }
#pragma unroll
    for (int g = 0; g < 4; ++g) {
      float p0 = exp2_asm(sa1[4 * g + 0] - mrun);
      float p1 = exp2_asm(sa1[4 * g + 1] - mrun);
      float p2 = exp2_asm(sa1[4 * g + 2] - mrun);
      float p3 = exp2_asm(sa1[4 * g + 3] - mrun);
      rs += (p0 + p1) + (p2 + p3);
      pk[1][g][0] = cvtpk_bf16(p0, p1);
      pk[1][g][1] = cvtpk_bf16(p2, p3);
    }
    rs += __shfl_xor(rs, 32);
    lrun += rs;

    // ---- P^T -> B-operand fragments via permlane32_swap ----
    bf16x8 pb[4];
#pragma unroll
    for (int tk = 0; tk < 2; ++tk)
#pragma unroll
      for (int par = 0; par < 2; ++par) {
        unsigned a0 = pk[tk][2 * par][0], b0 = pk[tk][2 * par + 1][0];
        unsigned a1 = pk[tk][2 * par][1], b1 = pk[tk][2 * par + 1][1];
        asm("v_permlane32_swap_b32 %0, %1" : "+v"(a0), "+v"(b0));
        asm("v_permlane32_swap_b32 %0, %1" : "+v"(a1), "+v"(b1));
        union { unsigned u[4]; bf16x8 v; } pw;
        pw.u[0] = a0; pw.u[1] = a1; pw.u[2] = b0; pw.u[3] = b1;
        pb[2 * tk + par] = pw.v;
      }

    // ---- O^T += mfma(V^T_A, P_B) ----
#pragma unroll
    for (int kb = 0; kb < 4; ++kb) {
      bf16x8 vf0 = *(const bf16x8*)(curb + 8192 + row0 * 128 + ((kb * 32 + hi16) ^ swz0));
      bf16x8 vf1 = *(const bf16x8*)(curb + 8192 + row1 * 128 + ((kb * 32 + hi16) ^ swz0));
      o0 = __builtin_amdgcn_mfma_f32_32x32x16_bf16(vf0, pb[kb], o0, 0, 0, 0);
      o1 = __builtin_amdgcn_mfma_f32_32x32x16_bf16(vf1, pb[kb], o1, 0, 0, 0);
    }
    __builtin_amdgcn_sched_barrier(0);
    asm volatile("s_waitcnt lgkmcnt(0)" ::: "memory");
    __builtin_amdgcn_s_barrier();
  }
#undef STAGE_KV

  // ---- epilogue: normalize lane's own q-row, split hi/lo, paired stores ----
  float inv = 1.0f / lrun;
  unsigned short* obase = Osp + mytok * N1_ + h * HD_;
#pragma unroll
  for (int dt = 0; dt < 2; ++dt) {
#pragma unroll
    for (int rp = 0; rp < 8; ++rp) {
      int r = rp * 2;
      float v0 = (dt ? o1[r] : o0[r]) * inv;
      float v1 = (dt ? o1[r + 1] : o0[r + 1]) * inv;
      unsigned hw = cvtpk_bf16(v0, v1);
      float l0 = v0 - bf2f((unsigned short)(hw & 0xffff));
      float l1 = v1 - bf2f((unsigned short)(hw >> 16));
      unsigned lw = cvtpk_bf16(l0, l1);
      int d = dt * 32 + (r & 3) + 8 * (r >> 2) + 4 * hi;
      *(unsigned*)(obase + d) = hw;
      *(unsigned*)(obase + 768 + d) = lw;
      *(unsigned*)(obase + 1536 + d) = hw;
    }
  }
}

// =====================================================================
extern "C" void kernel_launch(void* const* d_in, const int* in_sizes, int n_in,
                              void* d_out, int out_size, void* d_ws, size_t ws_size,
                              hipStream_t stream) {
  const float* x    = (const float*)d_in[0];
  const float* Wqkv = (const float*)d_in[1];
  const float* bqkv = (const float*)d_in[2];
  const float* Wout = (const float*)d_in[3];
  const float* bout = (const float*)d_in[4];

  char* ws = (char*)d_ws;
  unsigned short* qkvb  = (unsigned short*)(ws);                 // 75,497,472 B
  unsigned short* Osp   = (unsigned short*)(ws + 75497472L);     // 75,497,472 B
  unsigned short* xb    = (unsigned short*)(ws + 150994944L);    // 25,165,824 B
  unsigned short* Vt    = (unsigned short*)(ws + 150994944L);    // alias of xb
  unsigned short* WqkvT = (unsigned short*)(ws + 176160768L);    //  3,538,944 B
  unsigned short* Wt3   = (unsigned short*)(ws + 179699712L);    //  3,538,944 B

  // 128 KiB dynamic LDS opt-in for the 256^2 GEMMs
  hipFuncSetAttribute((const void*)gemm256<1>,
                      hipFuncAttributeMaxDynamicSharedMemorySize, 131072);
  hipFuncSetAttribute((const void*)gemm256<3>,
                      hipFuncAttributeMaxDynamicSharedMemorySize, 131072);

  k_cvt_x<<<6144, 256, 0, stream>>>(x, xb);
  k_prep_wqkvT<<<864, 256, 0, stream>>>(Wqkv, WqkvT);
  k_prep_wout<<<288, 256, 0, stream>>>(Wout, Wt3);
  gemm256<1><<<576, 512, 131072, stream>>>(xb, WqkvT, bqkv, (void*)qkvb, 768, 2304);
  k_transposeV2<<<1536, 256, 0, stream>>>(qkvb, Vt);
  attn_fused<<<1536, 256, 0, stream>>>(qkvb, Vt, Osp);
  gemm256<3><<<192, 512, 131072, stream>>>(Osp, Wt3, bout, d_out, 2304, 768);
}

// Round 6
// 210.997 us; speedup vs baseline: 1.3072x; 1.2448x over previous
//
#include <hip/hip_runtime.h>
#include <hip/hip_bf16.h>

// Problem constants
#define B_   16
#define N_   1024
#define C_   768
#define H_   12
#define HD_  64
#define M_   16384   // B*N tokens
#define N1_  2304    // 3*C
#define NEG_BIG (-1e30f)
#define LOG2E 1.4426950408889634f

typedef __attribute__((ext_vector_type(8))) _Float16 f16x8;  // 8 fp16 = 4 VGPR
typedef __attribute__((ext_vector_type(4))) float f32x4;
typedef __attribute__((ext_vector_type(16))) float f32x16;

// ---- fp16 helpers ----
__device__ __forceinline__ unsigned short f2h(float f) {   // RNE
  _Float16 h = (_Float16)f;
  union { _Float16 h; unsigned short u; } c; c.h = h; return c.u;
}
__device__ __forceinline__ unsigned int cvtpk_f16(float a, float b) {  // RTZ pack
  unsigned int r;
  asm("v_cvt_pkrtz_f16_f32 %0, %1, %2" : "=v"(r) : "v"(a), "v"(b));
  return r;
}
__device__ __forceinline__ float exp2_asm(float x) {
  float r;
  asm("v_exp_f32 %0, %1" : "=v"(r) : "v"(x));
  return r;
}

__device__ __forceinline__ void gload_lds16(const void* g, void* l) {
  __builtin_amdgcn_global_load_lds(
      (const __attribute__((address_space(1))) void*)g,
      (__attribute__((address_space(3))) void*)l, 16, 0, 0);
}

// =====================================================================
// Prep kernels
// =====================================================================

typedef __attribute__((ext_vector_type(8))) short u16x8;

__global__ __launch_bounds__(256) void k_cvt_x(const float* __restrict__ x,
                                               unsigned short* __restrict__ xh) {
  long i = ((long)blockIdx.x * 256 + threadIdx.x) * 8;
  float4 a = *(const float4*)(x + i);
  float4 b = *(const float4*)(x + i + 4);
  u16x8 v;
  v[0] = (short)f2h(a.x); v[1] = (short)f2h(a.y);
  v[2] = (short)f2h(a.z); v[3] = (short)f2h(a.w);
  v[4] = (short)f2h(b.x); v[5] = (short)f2h(b.y);
  v[6] = (short)f2h(b.z); v[7] = (short)f2h(b.w);
  *(u16x8*)(xh + i) = v;
}

// Wqkv [768,2304] fp32 -> WqkvT [2304,768] fp16
__global__ __launch_bounds__(256) void k_prep_wqkvT(const float* __restrict__ W,
                                                    unsigned short* __restrict__ Wt) {
  int tid = blockIdx.x * 256 + threadIdx.x;   // 96*2304 threads
  int n  = tid % N1_;
  int kc = tid / N1_;                          // 0..95
  u16x8 v;
#pragma unroll
  for (int j = 0; j < 8; ++j)
    v[j] = (short)f2h(W[(long)(kc * 8 + j) * N1_ + n]);
  *(u16x8*)(Wt + (long)n * C_ + kc * 8) = v;
}

// Wout [768,768] fp32 -> WoutT [768 n][768 k] fp16
__global__ __launch_bounds__(256) void k_prep_wout(const float* __restrict__ W,
                                                   unsigned short* __restrict__ Wt) {
  int tid = blockIdx.x * 256 + threadIdx.x;   // 96*768 threads
  int n  = tid % C_;
  int kc = tid / C_;                           // 0..95
  u16x8 v;
#pragma unroll
  for (int j = 0; j < 8; ++j)
    v[j] = (short)f2h(W[(long)(kc * 8 + j) * C_ + n]);
  *(u16x8*)(Wt + (long)n * C_ + kc * 8) = v;
}

// Transpose V region of qkvb into Vt [bh][64 d][1024 n] via LDS tile.
__global__ __launch_bounds__(256) void k_transposeV2(const unsigned short* __restrict__ qkvb,
                                                     unsigned short* __restrict__ Vt) {
  __shared__ unsigned char lt[16384];   // [64 d][128 n] 16-bit, swizzled
  int wid = (blockIdx.x & 7) * 192 + (blockIdx.x >> 3);   // XCD-chunked
  int bh = wid >> 3, nb = wid & 7;
  int b = bh / H_, h = bh % H_;
  long tok0 = (long)b * N_ + nb * 128;
  int t = threadIdx.x;
  int d0 = (t & 7) * 8;
#pragma unroll
  for (int it = 0; it < 4; ++it) {
    int nl = it * 32 + (t >> 3);
    u16x8 v = *(const u16x8*)(qkvb + (tok0 + nl) * N1_ + 1536 + h * HD_ + d0);
#pragma unroll
    for (int j = 0; j < 8; ++j) {
      int d = d0 + j;
      *(unsigned short*)(lt + d * 256 + ((nl * 2) ^ (((d >> 3) & 7) << 4))) =
          (unsigned short)v[j];
    }
  }
  __syncthreads();
  int l = t & 63, wv = t >> 6;
  int p = l & 1;
  int dbase = ((l >> 1) & 7) * 8 + (l >> 4) * 2;
#pragma unroll
  for (int rr = 0; rr < 4; ++rr) {
    int d = dbase + (rr & 1);
    int n0 = wv * 32 + (rr >> 1) * 16 + p * 8;
    u16x8 v = *(const u16x8*)(lt + d * 256 + ((n0 * 2) ^ (((d >> 3) & 7) << 4)));
    *(u16x8*)(Vt + ((long)bh * HD_ + d) * N_ + nb * 128 + n0) = v;
  }
}

// =====================================================================
// 256x256 8-phase GEMM (fp16): C[M,N] = A[M,K] * Bt[N,K]^T + bias
// 8 waves (2Mx4N), BK=64, 128 KiB LDS dbuf, staging spread 2 loads/phase,
// ONE counted vmcnt per K-tile at end of ph4. T3+T4+T5.
// STAGE 1: out fp16 qkvb via LDS-coalesced epilogue; STAGE 3: out fp32.
// =====================================================================
template <int STAGE>
__global__ __launch_bounds__(512, 2)
void gemm256(const unsigned short* __restrict__ A,
             const unsigned short* __restrict__ Bt,
             const float* __restrict__ bias,
             void* __restrict__ out, int Kdim, int Ndim) {
  extern __shared__ unsigned char lds[];   // 2 x (A 32K | B 32K) = 128 KiB
  const int t = threadIdx.x;
  const int l = t & 63, w = t >> 6;        // 8 waves
  const int g = l >> 4, lr = l & 15;
  const int wm = w >> 2, wn = w & 3;       // 2M x 4N wave grid
  const int NB = Ndim >> 8;
  const int wgid = (blockIdx.x & 7) * (gridDim.x >> 3) + (blockIdx.x >> 3);
  const int mb = wgid / NB, nb = wgid % NB;
  const long m0 = (long)mb << 8, n0 = (long)nb << 8;
  const int T = Kdim >> 6;                 // K-tiles of 64

  f32x4 acc[8][4];
  const f32x4 zz = {0.f, 0.f, 0.f, 0.f};
#pragma unroll
  for (int i = 0; i < 8; ++i)
#pragma unroll
    for (int j = 0; j < 4; ++j) acc[i][j] = zz;

  const long K2 = (long)Kdim * 2;
  const char* Ab = (const char*)A;
  const char* Bb = (const char*)Bt;
  const int sxcol = ((t & 7) * 16) ^ (((t >> 3) & 7) << 4);
  const int srowk = t >> 3;                // 0..63
  const int wvbase = w * 1024;

#define STAGE_A2(tile, i0)                                                   \
  {                                                                          \
    unsigned char* bufb_ = lds + ((tile) & 1) * 65536;                       \
    const char* As_ = Ab + (m0 + srowk) * K2 + (long)(tile) * 128 + sxcol;   \
    gload_lds16(As_ + (long)((i0) * 64) * K2,                                \
                (void*)(bufb_ + (i0) * 8192 + wvbase));                      \
    gload_lds16(As_ + (long)(((i0) + 1) * 64) * K2,                          \
                (void*)(bufb_ + ((i0) + 1) * 8192 + wvbase));                \
  }
#define STAGE_B2(tile, i0)                                                   \
  {                                                                          \
    unsigned char* bufb_ = lds + ((tile) & 1) * 65536 + 32768;               \
    const char* Bs_ = Bb + (n0 + srowk) * K2 + (long)(tile) * 128 + sxcol;   \
    gload_lds16(Bs_ + (long)((i0) * 64) * K2,                                \
                (void*)(bufb_ + (i0) * 8192 + wvbase));                      \
    gload_lds16(Bs_ + (long)(((i0) + 1) * 64) * K2,                          \
                (void*)(bufb_ + ((i0) + 1) * 8192 + wvbase));                \
  }

#define READ_A(ks, base)                                                     \
  _Pragma("unroll")                                                          \
  for (int mf = 0; mf < 8; ++mf) {                                           \
    int row = wm * 128 + mf * 16 + lr;                                       \
    af[mf] = *(const f16x8*)((base) + row * 128 +                            \
                             (((ks) * 64 + g * 16) ^ ((row & 7) << 4)));     \
  }
#define READ_B(ks, nh, base)                                                 \
  _Pragma("unroll")                                                          \
  for (int nf = 0; nf < 2; ++nf) {                                           \
    int row = wn * 64 + (nh) * 32 + nf * 16 + lr;                            \
    bfr[nf] = *(const f16x8*)((base) + 32768 + row * 128 +                   \
                              (((ks) * 64 + g * 16) ^ ((row & 7) << 4)));    \
  }
#define MFMA16(nh)                                                           \
  _Pragma("unroll")                                                          \
  for (int mf = 0; mf < 8; ++mf) {                                           \
    acc[mf][(nh) * 2 + 0] = __builtin_amdgcn_mfma_f32_16x16x32_f16(          \
        af[mf], bfr[0], acc[mf][(nh) * 2 + 0], 0, 0, 0);                     \
    acc[mf][(nh) * 2 + 1] = __builtin_amdgcn_mfma_f32_16x16x32_f16(          \
        af[mf], bfr[1], acc[mf][(nh) * 2 + 1], 0, 0, 0);                     \
  }
#define BAR()  __builtin_amdgcn_s_barrier(); asm volatile("" ::: "memory")

  // prologue: fully stage tiles 0 and 1 (16 loads); wait tile-0 set
  STAGE_A2(0, 0); STAGE_A2(0, 2); STAGE_B2(0, 0); STAGE_B2(0, 2);
  STAGE_A2(1, 0); STAGE_A2(1, 2); STAGE_B2(1, 0); STAGE_B2(1, 2);
  asm volatile("s_waitcnt vmcnt(8)" ::: "memory");
  BAR();

  for (int tt = 0; tt < T; ++tt) {
    unsigned char* base = lds + (tt & 1) * 65536;
    f16x8 af[8], bfr[2];
    // ---- ph1 ----
    READ_A(0, base);
    READ_B(0, 0, base);
    if (tt >= 1 && tt + 1 < T) STAGE_B2(tt + 1, 0);
    BAR();
    __builtin_amdgcn_s_setprio(1);
    MFMA16(0);
    __builtin_amdgcn_s_setprio(0);
    BAR();
    // ---- ph2 ----
    READ_B(0, 1, base);
    if (tt >= 1 && tt + 1 < T) STAGE_B2(tt + 1, 2);
    BAR();
    __builtin_amdgcn_s_setprio(1);
    MFMA16(1);
    __builtin_amdgcn_s_setprio(0);
    BAR();
    // ---- ph3 ----
    READ_A(1, base);
    READ_B(1, 0, base);
    if (tt >= 1 && tt + 1 < T) STAGE_A2(tt + 1, 2);
    BAR();
    __builtin_amdgcn_s_setprio(1);
    MFMA16(0);
    __builtin_amdgcn_s_setprio(0);
    BAR();
    // ---- ph4 ----
    READ_B(1, 1, base);
    if (tt + 2 < T) STAGE_A2(tt + 2, 0);
    BAR();
    __builtin_amdgcn_s_setprio(1);
    MFMA16(1);
    __builtin_amdgcn_s_setprio(0);
    if (tt + 1 < T) {
      if (tt + 2 < T) { asm volatile("s_waitcnt vmcnt(2)" ::: "memory"); }
      else            { asm volatile("s_waitcnt vmcnt(0)" ::: "memory"); }
    }
    BAR();
  }
#undef STAGE_A2
#undef STAGE_B2
#undef READ_A
#undef READ_B
#undef MFMA16

  // ---- epilogue ----
  if (STAGE == 1) {
    float sc = (n0 < 768) ? 0.125f * LOG2E : 1.0f;  // Q pre-scale (exp2 domain)
    unsigned short* cl = (unsigned short*)lds;
#pragma unroll
    for (int j = 0; j < 4; ++j) {
      int col = wn * 64 + (j >> 1) * 32 + (j & 1) * 16 + lr;
      float bv = bias[(int)n0 + col];
#pragma unroll
      for (int mf = 0; mf < 8; ++mf)
#pragma unroll
        for (int r = 0; r < 4; ++r) {
          int row = wm * 128 + mf * 16 + g * 4 + r;
          cl[row * 256 + col] = f2h((acc[mf][j][r] + bv) * sc);
        }
    }
    __syncthreads();
    unsigned short* o = (unsigned short*)out;
#pragma unroll
    for (int it = 0; it < 16; ++it) {
      int idx = it * 4096 + t * 8;         // shorts
      int row = idx >> 8;
      int col = idx & 255;
      *(u16x8*)(o + (m0 + row) * N1_ + n0 + col) = *(const u16x8*)(cl + idx);
    }
  } else {
    float* o = (float*)out;
#pragma unroll
    for (int j = 0; j < 4; ++j) {
      int col = (int)n0 + wn * 64 + (j >> 1) * 32 + (j & 1) * 16 + lr;
      float bv = bias[col];
#pragma unroll
      for (int mf = 0; mf < 8; ++mf)
#pragma unroll
        for (int r = 0; r < 4; ++r) {
          long rowm = m0 + wm * 128 + mf * 16 + g * 4 + r;
          o[rowm * C_ + col] = acc[mf][j][r] + bv;
        }
    }
  }
#undef BAR
}

// =====================================================================
// Fused flash attention, 32x32x16 fp16 MFMA, fully-transposed form.
// Swizzle reverted to period-8/16B. Softmax max/sum via pairwise trees.
// Output: plain fp16 O [16384][768].
// =====================================================================
__global__ __launch_bounds__(256, 3)
void attn_fused(const unsigned short* __restrict__ qkvb,
                const unsigned short* __restrict__ Vt,
                unsigned short* __restrict__ Ofp) {
  __shared__ unsigned char lds[32768];  // 2 x (K 8K | V 8K)
  const int t = threadIdx.x, l = t & 63, w = t >> 6;
  const int q32 = l & 31;
  const int hi = l >> 5;
  const int hi16 = hi * 16;
  const int wid = (blockIdx.x & 7) * 192 + (blockIdx.x >> 3);
  const int bh = wid >> 3, qb = wid & 7;
  const int b = bh / H_, h = bh % H_;
  const long tok0 = (long)b * N_;
  const int q0 = qb * 128 + w * 32;
  const long mytok = tok0 + q0 + q32;

  // Q B-fragments (pre-scaled by 0.125*log2e in stage-1)
  f16x8 qa[4];
#pragma unroll
  for (int cs = 0; cs < 4; ++cs)
    qa[cs] = *(const f16x8*)(qkvb + mytok * N1_ + h * HD_ + cs * 16 + hi * 8);

  const f32x16 zz16 = {0.f};
  f32x16 o0 = zz16, o1 = zz16;   // O^T: d 0..31 / 32..63 for lane's q
  float mrun = NEG_BIG, lrun = 0.f;

  const int row0 = q32, row1 = 32 + q32;
  const int swz0 = (q32 & 7) << 4;    // period-8 / 16B XOR (reverted)

  const int sxs = ((t & 7) * 16) ^ (((t >> 3) & 7) << 4);
  const int wbase = (t & 192) * 16;
  const char* Vg = (const char*)(Vt + (long)bh * HD_ * N_);
  const char* Kg = (const char*)qkvb + ((tok0)*N1_ + C_ + h * HD_) * 2;

#define STAGE_KV(kv0, buf)                                                  \
  {                                                                         \
    _Pragma("unroll")                                                       \
    for (int i = 0; i < 2; ++i) {                                           \
      int row = i * 32 + (t >> 3);                                          \
      gload_lds16(Kg + ((long)(kv0 + row) * N1_) * 2 + sxs,                 \
                  (void*)((buf) + i * 4096 + wbase));                       \
    }                                                                       \
    _Pragma("unroll")                                                       \
    for (int i = 0; i < 2; ++i) {                                           \
      int row = i * 32 + (t >> 3);                                          \
      gload_lds16(Vg + ((long)row * N_ + (kv0)) * 2 + sxs,                  \
                  (void*)((buf) + 8192 + i * 4096 + wbase));                \
    }                                                                       \
  }

  STAGE_KV(0, lds);

#pragma unroll 2
  for (int tt = 0; tt < 16; ++tt) {
    unsigned char* curb = lds + (tt & 1) * 16384;
    unsigned char* nxtb = lds + ((tt & 1) ^ 1) * 16384;
    if (tt < 15) {
      STAGE_KV((tt + 1) * 64, nxtb);
      asm volatile("s_waitcnt vmcnt(4)" ::: "memory");
    } else {
      asm volatile("s_waitcnt vmcnt(0)" ::: "memory");
    }
    __builtin_amdgcn_s_barrier();
    __builtin_amdgcn_sched_barrier(0);

    // ---- S^T = mfma(K_A, Q_B) ----
    f32x16 sa0 = zz16, sa1 = zz16;
#pragma unroll
    for (int cs = 0; cs < 4; ++cs) {
      f16x8 kf0 = *(const f16x8*)(curb + row0 * 128 + ((cs * 32 + hi16) ^ swz0));
      f16x8 kf1 = *(const f16x8*)(curb + row1 * 128 + ((cs * 32 + hi16) ^ swz0));
      sa0 = __builtin_amdgcn_mfma_f32_32x32x16_f16(kf0, qa[cs], sa0, 0, 0, 0);
      sa1 = __builtin_amdgcn_mfma_f32_32x32x16_f16(kf1, qa[cs], sa1, 0, 0, 0);
    }

    // ---- in-lane online softmax (log2 domain), tree reductions ----
    float tm[16];
#pragma unroll
    for (int i = 0; i < 16; ++i) tm[i] = fmaxf(sa0[i], sa1[i]);
#pragma unroll
    for (int s = 8; s >= 1; s >>= 1)
#pragma unroll
      for (int i = 0; i < s; ++i) tm[i] = fmaxf(tm[i], tm[i + s]);
    float mx = tm[0];
    mx = fmaxf(mx, __shfl_xor(mx, 32));
    if (!__all(mx <= mrun + 8.f)) {           // defer-max
      float mn = fmaxf(mrun, mx);
      float al = exp2_asm(mrun - mn);
      mrun = mn;
      lrun *= al;
      o0 *= al;
      o1 *= al;
    }
    float p0a[16], p1a[16];
#pragma unroll
    for (int i = 0; i < 16; ++i) p0a[i] = exp2_asm(sa0[i] - mrun);
#pragma unroll
    for (int i = 0; i < 16; ++i) p1a[i] = exp2_asm(sa1[i] - mrun);
    unsigned pk[2][4][2];
#pragma unroll
    for (int g = 0; g < 4; ++g) {
      pk[0][g][0] = cvtpk_f16(p0a[4 * g + 0], p0a[4 * g + 1]);
      pk[0][g][1] = cvtpk_f16(p0a[4 * g + 2], p0a[4 * g + 3]);
      pk[1][g][0] = cvtpk_f16(p1a[4 * g + 0], p1a[4 * g + 1]);
      pk[1][g][1] = cvtpk_f16(p1a[4 * g + 2], p1a[4 * g + 3]);
    }
    float ts[16];
#pragma unroll
    for (int i = 0; i < 16; ++i) ts[i] = p0a[i] + p1a[i];
#pragma unroll
    for (int s = 8; s >= 1; s >>= 1)
#pragma unroll
      for (int i = 0; i < s; ++i) ts[i] += ts[i + s];
    float rs = ts[0];
    rs += __shfl_xor(rs, 32);
    lrun += rs;

    // ---- P^T -> B-operand fragments via permlane32_swap ----
    f16x8 pb[4];
#pragma unroll
    for (int tk = 0; tk < 2; ++tk)
#pragma unroll
      for (int par = 0; par < 2; ++par) {
        unsigned a0 = pk[tk][2 * par][0], b0 = pk[tk][2 * par + 1][0];
        unsigned a1 = pk[tk][2 * par][1], b1 = pk[tk][2 * par + 1][1];
        asm("v_permlane32_swap_b32 %0, %1" : "+v"(a0), "+v"(b0));
        asm("v_permlane32_swap_b32 %0, %1" : "+v"(a1), "+v"(b1));
        union { unsigned u[4]; f16x8 v; } pw;
        pw.u[0] = a0; pw.u[1] = a1; pw.u[2] = b0; pw.u[3] = b1;
        pb[2 * tk + par] = pw.v;
      }

    // ---- O^T += mfma(V^T_A, P_B) ----
#pragma unroll
    for (int kb = 0; kb < 4; ++kb) {
      f16x8 vf0 = *(const f16x8*)(curb + 8192 + row0 * 128 + ((kb * 32 + hi16) ^ swz0));
      f16x8 vf1 = *(const f16x8*)(curb + 8192 + row1 * 128 + ((kb * 32 + hi16) ^ swz0));
      o0 = __builtin_amdgcn_mfma_f32_32x32x16_f16(vf0, pb[kb], o0, 0, 0, 0);
      o1 = __builtin_amdgcn_mfma_f32_32x32x16_f16(vf1, pb[kb], o1, 0, 0, 0);
    }
    __builtin_amdgcn_sched_barrier(0);
    asm volatile("s_waitcnt lgkmcnt(0)" ::: "memory");
    __builtin_amdgcn_s_barrier();
  }
#undef STAGE_KV

  // ---- epilogue: normalize, fp16 pack, paired dword stores ----
  float inv = 1.0f / lrun;
  unsigned short* obase = Ofp + mytok * C_ + h * HD_;
#pragma unroll
  for (int dt = 0; dt < 2; ++dt) {
#pragma unroll
    for (int rp = 0; rp < 8; ++rp) {
      int r = rp * 2;
      float v0 = (dt ? o1[r] : o0[r]) * inv;
      float v1 = (dt ? o1[r + 1] : o0[r + 1]) * inv;
      unsigned hw = cvtpk_f16(v0, v1);
      int d = dt * 32 + (r & 3) + 8 * (r >> 2) + 4 * hi;
      *(unsigned*)(obase + d) = hw;
    }
  }
}

// =====================================================================
extern "C" void kernel_launch(void* const* d_in, const int* in_sizes, int n_in,
                              void* d_out, int out_size, void* d_ws, size_t ws_size,
                              hipStream_t stream) {
  const float* x    = (const float*)d_in[0];
  const float* Wqkv = (const float*)d_in[1];
  const float* bqkv = (const float*)d_in[2];
  const float* Wout = (const float*)d_in[3];
  const float* bout = (const float*)d_in[4];

  char* ws = (char*)d_ws;
  unsigned short* qkvb  = (unsigned short*)(ws);                 // 75,497,472 B
  unsigned short* Ofp   = (unsigned short*)(ws + 75497472L);     // 25,165,824 B
  unsigned short* xh    = (unsigned short*)(ws + 100663296L);    // 25,165,824 B
  unsigned short* Vt    = (unsigned short*)(ws + 100663296L);    // alias of xh
  unsigned short* WqkvT = (unsigned short*)(ws + 125829120L);    //  3,538,944 B
  unsigned short* WoutT = (unsigned short*)(ws + 129368064L);    //  1,179,648 B
  // total: 130,547,712 B

  hipFuncSetAttribute((const void*)gemm256<1>,
                      hipFuncAttributeMaxDynamicSharedMemorySize, 131072);
  hipFuncSetAttribute((const void*)gemm256<3>,
                      hipFuncAttributeMaxDynamicSharedMemorySize, 131072);

  k_cvt_x<<<6144, 256, 0, stream>>>(x, xh);
  k_prep_wqkvT<<<864, 256, 0, stream>>>(Wqkv, WqkvT);
  k_prep_wout<<<288, 256, 0, stream>>>(Wout, WoutT);
  gemm256<1><<<576, 512, 131072, stream>>>(xh, WqkvT, bqkv, (void*)qkvb, 768, 2304);
  k_transposeV2<<<1536, 256, 0, stream>>>(qkvb, Vt);
  attn_fused<<<1536, 256, 0, stream>>>(qkvb, Vt, Ofp);
  gemm256<3><<<192, 512, 131072, stream>>>(Ofp, WoutT, bout, d_out, 768, 768);
}

// Round 7
// 188.840 us; speedup vs baseline: 1.4606x; 1.1173x over previous
//
#include <hip/hip_runtime.h>
#include <hip/hip_bf16.h>

// Problem constants
#define B_   16
#define N_   1024
#define C_   768
#define H_   12
#define HD_  64
#define M_   16384   // B*N tokens
#define N1_  2304    // 3*C
#define NEG_BIG (-1e30f)
#define LOG2E 1.4426950408889634f

typedef __attribute__((ext_vector_type(8))) _Float16 f16x8;  // 8 fp16 = 4 VGPR
typedef __attribute__((ext_vector_type(4))) float f32x4;
typedef __attribute__((ext_vector_type(16))) float f32x16;

// ---- fp16 helpers ----
__device__ __forceinline__ unsigned short f2h(float f) {   // RNE
  _Float16 h = (_Float16)f;
  union { _Float16 h; unsigned short u; } c; c.h = h; return c.u;
}
__device__ __forceinline__ unsigned int cvtpk_f16(float a, float b) {  // RTZ pack
  unsigned int r;
  asm("v_cvt_pkrtz_f16_f32 %0, %1, %2" : "=v"(r) : "v"(a), "v"(b));
  return r;
}
__device__ __forceinline__ float exp2_asm(float x) {
  float r;
  asm("v_exp_f32 %0, %1" : "=v"(r) : "v"(x));
  return r;
}

__device__ __forceinline__ void gload_lds16(const void* g, void* l) {
  __builtin_amdgcn_global_load_lds(
      (const __attribute__((address_space(1))) void*)g,
      (__attribute__((address_space(3))) void*)l, 16, 0, 0);
}

// =====================================================================
// Prep kernels
// =====================================================================

typedef __attribute__((ext_vector_type(8))) short u16x8;

__global__ __launch_bounds__(256) void k_cvt_x(const float* __restrict__ x,
                                               unsigned short* __restrict__ xh) {
  long i = ((long)blockIdx.x * 256 + threadIdx.x) * 8;
  float4 a = *(const float4*)(x + i);
  float4 b = *(const float4*)(x + i + 4);
  u16x8 v;
  v[0] = (short)f2h(a.x); v[1] = (short)f2h(a.y);
  v[2] = (short)f2h(a.z); v[3] = (short)f2h(a.w);
  v[4] = (short)f2h(b.x); v[5] = (short)f2h(b.y);
  v[6] = (short)f2h(b.z); v[7] = (short)f2h(b.w);
  *(u16x8*)(xh + i) = v;
}

// Wqkv [768,2304] fp32 -> WqkvT [2304,768] fp16
__global__ __launch_bounds__(256) void k_prep_wqkvT(const float* __restrict__ W,
                                                    unsigned short* __restrict__ Wt) {
  int tid = blockIdx.x * 256 + threadIdx.x;   // 96*2304 threads
  int n  = tid % N1_;
  int kc = tid / N1_;                          // 0..95
  u16x8 v;
#pragma unroll
  for (int j = 0; j < 8; ++j)
    v[j] = (short)f2h(W[(long)(kc * 8 + j) * N1_ + n]);
  *(u16x8*)(Wt + (long)n * C_ + kc * 8) = v;
}

// Wout [768,768] fp32 -> WoutT [768 n][768 k] fp16
__global__ __launch_bounds__(256) void k_prep_wout(const float* __restrict__ W,
                                                   unsigned short* __restrict__ Wt) {
  int tid = blockIdx.x * 256 + threadIdx.x;   // 96*768 threads
  int n  = tid % C_;
  int kc = tid / C_;                           // 0..95
  u16x8 v;
#pragma unroll
  for (int j = 0; j < 8; ++j)
    v[j] = (short)f2h(W[(long)(kc * 8 + j) * C_ + n]);
  *(u16x8*)(Wt + (long)n * C_ + kc * 8) = v;
}

// Transpose V region of qkvb into Vt [bh][64 d][1024 n] via LDS tile.
__global__ __launch_bounds__(256) void k_transposeV2(const unsigned short* __restrict__ qkvb,
                                                     unsigned short* __restrict__ Vt) {
  __shared__ unsigned char lt[16384];   // [64 d][128 n] 16-bit, swizzled
  int wid = (blockIdx.x & 7) * 192 + (blockIdx.x >> 3);   // XCD-chunked
  int bh = wid >> 3, nb = wid & 7;
  int b = bh / H_, h = bh % H_;
  long tok0 = (long)b * N_ + nb * 128;
  int t = threadIdx.x;
  int d0 = (t & 7) * 8;
#pragma unroll
  for (int it = 0; it < 4; ++it) {
    int nl = it * 32 + (t >> 3);
    u16x8 v = *(const u16x8*)(qkvb + (tok0 + nl) * N1_ + 1536 + h * HD_ + d0);
#pragma unroll
    for (int j = 0; j < 8; ++j) {
      int d = d0 + j;
      *(unsigned short*)(lt + d * 256 + ((nl * 2) ^ (((d >> 3) & 7) << 4))) =
          (unsigned short)v[j];
    }
  }
  __syncthreads();
  int l = t & 63, wv = t >> 6;
  int p = l & 1;
  int dbase = ((l >> 1) & 7) * 8 + (l >> 4) * 2;
#pragma unroll
  for (int rr = 0; rr < 4; ++rr) {
    int d = dbase + (rr & 1);
    int n0 = wv * 32 + (rr >> 1) * 16 + p * 8;
    u16x8 v = *(const u16x8*)(lt + d * 256 + ((n0 * 2) ^ (((d >> 3) & 7) << 4)));
    *(u16x8*)(Vt + ((long)bh * HD_ + d) * N_ + nb * 128 + n0) = v;
  }
}

// =====================================================================
// 128x128 GEMM (m97 2-barrier structure, fp16): C = A * Bt^T + bias
// 4 waves (2x2), BK=64, 32 KiB static LDS, gload_lds w/ pre-swizzled src.
// 4 blocks/CU co-residency hides barrier drains (m114 overlap).
// STAGE 1: fp16 out via LDS-coalesced epilogue; STAGE 3: fp32 direct.
// =====================================================================
template <int STAGE>
__global__ __launch_bounds__(256, 4)
void gemm128(const unsigned short* __restrict__ A,
             const unsigned short* __restrict__ Bt,
             const float* __restrict__ bias,
             void* __restrict__ out, int Kdim, int Ndim) {
  __shared__ unsigned char lds[32768];   // A tile 16K | B tile 16K
  const int t = threadIdx.x;
  const int l = t & 63, w = t >> 6;
  const int g = l >> 4, lr = l & 15;
  const int NB = Ndim >> 7;
  const int wgid = (blockIdx.x & 7) * (gridDim.x >> 3) + (blockIdx.x >> 3);
  const int mb = wgid / NB, nb = wgid % NB;
  const long m0 = (long)mb << 7, n0 = (long)nb << 7;
  const int wm = w >> 1, wn = w & 1;

  f32x4 acc[4][4];
  const f32x4 zz = {0.f, 0.f, 0.f, 0.f};
#pragma unroll
  for (int i = 0; i < 4; ++i)
#pragma unroll
    for (int j = 0; j < 4; ++j) acc[i][j] = zz;

  // staging slot decode: slot s = i*4096 + t*16 ; LDS linear, swizzled SOURCE
  int srow[4], sx[4];
#pragma unroll
  for (int i = 0; i < 4; ++i) {
    int s = i * 4096 + t * 16;
    int row = s >> 7;
    srow[i] = row;
    sx[i] = (s & 127) ^ ((row & 7) << 4);
  }
  const char* Ab = (const char*)A;
  const char* Bb = (const char*)Bt;
  const long K2 = (long)Kdim * 2;
  const int wbase = (t & 192) * 16;   // wave-uniform LDS base (w*1024)

  for (int kt = 0; kt < Kdim; kt += 64) {
#pragma unroll
    for (int i = 0; i < 4; ++i) {
      const char* src = Ab + (m0 + srow[i]) * K2 + kt * 2 + sx[i];
      gload_lds16(src, (void*)(lds + i * 4096 + wbase));
    }
#pragma unroll
    for (int i = 0; i < 4; ++i) {
      const char* src = Bb + (n0 + srow[i]) * K2 + kt * 2 + sx[i];
      gload_lds16(src, (void*)(lds + 16384 + i * 4096 + wbase));
    }
    __syncthreads();
#pragma unroll
    for (int ks = 0; ks < 2; ++ks) {
      f16x8 af[4], bfr[4];
#pragma unroll
      for (int mi = 0; mi < 4; ++mi) {
        int row = wm * 64 + mi * 16 + lr;
        int off = row * 128 + ((ks * 64 + g * 16) ^ ((row & 7) << 4));
        af[mi] = *(const f16x8*)(lds + off);
      }
#pragma unroll
      for (int ni = 0; ni < 4; ++ni) {
        int row = wn * 64 + ni * 16 + lr;
        int off = 16384 + row * 128 + ((ks * 64 + g * 16) ^ ((row & 7) << 4));
        bfr[ni] = *(const f16x8*)(lds + off);
      }
#pragma unroll
      for (int mi = 0; mi < 4; ++mi)
#pragma unroll
        for (int ni = 0; ni < 4; ++ni)
          acc[mi][ni] = __builtin_amdgcn_mfma_f32_16x16x32_f16(
              af[mi], bfr[ni], acc[mi][ni], 0, 0, 0);
    }
    __syncthreads();
  }

  // ---- epilogue ----
  if (STAGE == 1) {
    // stage C-tile (128x128 fp16 = 32 KiB) in LDS, then coalesced stores
    float sc = (n0 < 768) ? 0.125f * LOG2E : 1.0f;  // Q pre-scale (exp2 dom)
    unsigned short* cl = (unsigned short*)lds;
#pragma unroll
    for (int ni = 0; ni < 4; ++ni) {
      int col = wn * 64 + ni * 16 + lr;
      float bv = bias[(int)n0 + col];
#pragma unroll
      for (int mi = 0; mi < 4; ++mi)
#pragma unroll
        for (int r = 0; r < 4; ++r) {
          int row = wm * 64 + mi * 16 + g * 4 + r;
          cl[row * 128 + col] = f2h((acc[mi][ni][r] + bv) * sc);
        }
    }
    __syncthreads();
    unsigned short* o = (unsigned short*)out;
#pragma unroll
    for (int it = 0; it < 8; ++it) {
      int idx = it * 2048 + t * 8;         // shorts
      int row = idx >> 7;
      int col = idx & 127;
      *(u16x8*)(o + (m0 + row) * N1_ + n0 + col) = *(const u16x8*)(cl + idx);
    }
  } else {
    float* o = (float*)out;
#pragma unroll
    for (int ni = 0; ni < 4; ++ni) {
      int col = (int)n0 + wn * 64 + ni * 16 + lr;
      float bv = bias[col];
#pragma unroll
      for (int mi = 0; mi < 4; ++mi)
#pragma unroll
        for (int r = 0; r < 4; ++r) {
          long rowm = m0 + wm * 64 + mi * 16 + g * 4 + r;
          o[rowm * C_ + col] = acc[mi][ni][r] + bv;
        }
    }
  }
}

// =====================================================================
// Fused flash attention, 32x32x16 fp16 MFMA, fully-transposed form.
// 4 blocks/CU co-residency; max3-fused fmax tree.
// =====================================================================
__global__ __launch_bounds__(256, 4)
void attn_fused(const unsigned short* __restrict__ qkvb,
                const unsigned short* __restrict__ Vt,
                unsigned short* __restrict__ Ofp) {
  __shared__ unsigned char lds[32768];  // 2 x (K 8K | V 8K)
  const int t = threadIdx.x, l = t & 63, w = t >> 6;
  const int q32 = l & 31;
  const int hi = l >> 5;
  const int hi16 = hi * 16;
  const int wid = (blockIdx.x & 7) * 192 + (blockIdx.x >> 3);
  const int bh = wid >> 3, qb = wid & 7;
  const int b = bh / H_, h = bh % H_;
  const long tok0 = (long)b * N_;
  const int q0 = qb * 128 + w * 32;
  const long mytok = tok0 + q0 + q32;

  // Q B-fragments (pre-scaled by 0.125*log2e in stage-1)
  f16x8 qa[4];
#pragma unroll
  for (int cs = 0; cs < 4; ++cs)
    qa[cs] = *(const f16x8*)(qkvb + mytok * N1_ + h * HD_ + cs * 16 + hi * 8);

  const f32x16 zz16 = {0.f};
  f32x16 o0 = zz16, o1 = zz16;   // O^T: d 0..31 / 32..63 for lane's q
  float mrun = NEG_BIG, lrun = 0.f;

  const int row0 = q32, row1 = 32 + q32;
  const int swz0 = (q32 & 7) << 4;    // period-8 / 16B XOR

  const int sxs = ((t & 7) * 16) ^ (((t >> 3) & 7) << 4);
  const int wbase = (t & 192) * 16;
  const char* Vg = (const char*)(Vt + (long)bh * HD_ * N_);
  const char* Kg = (const char*)qkvb + ((tok0)*N1_ + C_ + h * HD_) * 2;

#define STAGE_KV(kv0, buf)                                                  \
  {                                                                         \
    _Pragma("unroll")                                                       \
    for (int i = 0; i < 2; ++i) {                                           \
      int row = i * 32 + (t >> 3);                                          \
      gload_lds16(Kg + ((long)(kv0 + row) * N1_) * 2 + sxs,                 \
                  (void*)((buf) + i * 4096 + wbase));                       \
    }                                                                       \
    _Pragma("unroll")                                                       \
    for (int i = 0; i < 2; ++i) {                                           \
      int row = i * 32 + (t >> 3);                                          \
      gload_lds16(Vg + ((long)row * N_ + (kv0)) * 2 + sxs,                  \
                  (void*)((buf) + 8192 + i * 4096 + wbase));                \
    }                                                                       \
  }

  STAGE_KV(0, lds);

#pragma unroll 2
  for (int tt = 0; tt < 16; ++tt) {
    unsigned char* curb = lds + (tt & 1) * 16384;
    unsigned char* nxtb = lds + ((tt & 1) ^ 1) * 16384;
    if (tt < 15) {
      STAGE_KV((tt + 1) * 64, nxtb);
      asm volatile("s_waitcnt vmcnt(4)" ::: "memory");
    } else {
      asm volatile("s_waitcnt vmcnt(0)" ::: "memory");
    }
    __builtin_amdgcn_s_barrier();
    __builtin_amdgcn_sched_barrier(0);

    // ---- S^T = mfma(K_A, Q_B) ----
    f32x16 sa0 = zz16, sa1 = zz16;
#pragma unroll
    for (int cs = 0; cs < 4; ++cs) {
      f16x8 kf0 = *(const f16x8*)(curb + row0 * 128 + ((cs * 32 + hi16) ^ swz0));
      f16x8 kf1 = *(const f16x8*)(curb + row1 * 128 + ((cs * 32 + hi16) ^ swz0));
      sa0 = __builtin_amdgcn_mfma_f32_32x32x16_f16(kf0, qa[cs], sa0, 0, 0, 0);
      sa1 = __builtin_amdgcn_mfma_f32_32x32x16_f16(kf1, qa[cs], sa1, 0, 0, 0);
    }

    // ---- in-lane online softmax (log2 domain), max3-fused tree ----
    float tm[11];
#pragma unroll
    for (int i = 0; i < 5; ++i)
      tm[i] = fmaxf(fmaxf(sa0[3 * i], sa0[3 * i + 1]), sa0[3 * i + 2]);
    tm[5] = fmaxf(sa0[15], sa1[0]);
#pragma unroll
    for (int i = 0; i < 5; ++i)
      tm[6 + i] = fmaxf(fmaxf(sa1[3 * i + 1], sa1[3 * i + 2]), sa1[3 * i + 3]);
    float u0 = fmaxf(fmaxf(tm[0], tm[1]), tm[2]);
    float u1 = fmaxf(fmaxf(tm[3], tm[4]), tm[5]);
    float u2 = fmaxf(fmaxf(tm[6], tm[7]), tm[8]);
    float u3 = fmaxf(fmaxf(tm[9], tm[10]), u0);
    float mx = fmaxf(fmaxf(u1, u2), u3);
    mx = fmaxf(mx, __shfl_xor(mx, 32));
    if (!__all(mx <= mrun + 8.f)) {           // defer-max
      float mn = fmaxf(mrun, mx);
      float al = exp2_asm(mrun - mn);
      mrun = mn;
      lrun *= al;
      o0 *= al;
      o1 *= al;
    }
    float p0a[16], p1a[16];
#pragma unroll
    for (int i = 0; i < 16; ++i) p0a[i] = exp2_asm(sa0[i] - mrun);
#pragma unroll
    for (int i = 0; i < 16; ++i) p1a[i] = exp2_asm(sa1[i] - mrun);
    unsigned pk[2][4][2];
#pragma unroll
    for (int g = 0; g < 4; ++g) {
      pk[0][g][0] = cvtpk_f16(p0a[4 * g + 0], p0a[4 * g + 1]);
      pk[0][g][1] = cvtpk_f16(p0a[4 * g + 2], p0a[4 * g + 3]);
      pk[1][g][0] = cvtpk_f16(p1a[4 * g + 0], p1a[4 * g + 1]);
      pk[1][g][1] = cvtpk_f16(p1a[4 * g + 2], p1a[4 * g + 3]);
    }
    float ts[16];
#pragma unroll
    for (int i = 0; i < 16; ++i) ts[i] = p0a[i] + p1a[i];
#pragma unroll
    for (int s = 8; s >= 1; s >>= 1)
#pragma unroll
      for (int i = 0; i < s; ++i) ts[i] += ts[i + s];
    float rs = ts[0];
    rs += __shfl_xor(rs, 32);
    lrun += rs;

    // ---- P^T -> B-operand fragments via permlane32_swap ----
    f16x8 pb[4];
#pragma unroll
    for (int tk = 0; tk < 2; ++tk)
#pragma unroll
      for (int par = 0; par < 2; ++par) {
        unsigned a0 = pk[tk][2 * par][0], b0 = pk[tk][2 * par + 1][0];
        unsigned a1 = pk[tk][2 * par][1], b1 = pk[tk][2 * par + 1][1];
        asm("v_permlane32_swap_b32 %0, %1" : "+v"(a0), "+v"(b0));
        asm("v_permlane32_swap_b32 %0, %1" : "+v"(a1), "+v"(b1));
        union { unsigned u[4]; f16x8 v; } pw;
        pw.u[0] = a0; pw.u[1] = a1; pw.u[2] = b0; pw.u[3] = b1;
        pb[2 * tk + par] = pw.v;
      }

    // ---- O^T += mfma(V^T_A, P_B) ----
#pragma unroll
    for (int kb = 0; kb < 4; ++kb) {
      f16x8 vf0 = *(const f16x8*)(curb + 8192 + row0 * 128 + ((kb * 32 + hi16) ^ swz0));
      f16x8 vf1 = *(const f16x8*)(curb + 8192 + row1 * 128 + ((kb * 32 + hi16) ^ swz0));
      o0 = __builtin_amdgcn_mfma_f32_32x32x16_f16(vf0, pb[kb], o0, 0, 0, 0);
      o1 = __builtin_amdgcn_mfma_f32_32x32x16_f16(vf1, pb[kb], o1, 0, 0, 0);
    }
    __builtin_amdgcn_sched_barrier(0);
    asm volatile("s_waitcnt lgkmcnt(0)" ::: "memory");
    __builtin_amdgcn_s_barrier();
  }
#undef STAGE_KV

  // ---- epilogue: normalize, fp16 pack, paired dword stores ----
  float inv = 1.0f / lrun;
  unsigned short* obase = Ofp + mytok * C_ + h * HD_;
#pragma unroll
  for (int dt = 0; dt < 2; ++dt) {
#pragma unroll
    for (int rp = 0; rp < 8; ++rp) {
      int r = rp * 2;
      float v0 = (dt ? o1[r] : o0[r]) * inv;
      float v1 = (dt ? o1[r + 1] : o0[r + 1]) * inv;
      unsigned hw = cvtpk_f16(v0, v1);
      int d = dt * 32 + (r & 3) + 8 * (r >> 2) + 4 * hi;
      *(unsigned*)(obase + d) = hw;
    }
  }
}

// =====================================================================
extern "C" void kernel_launch(void* const* d_in, const int* in_sizes, int n_in,
                              void* d_out, int out_size, void* d_ws, size_t ws_size,
                              hipStream_t stream) {
  const float* x    = (const float*)d_in[0];
  const float* Wqkv = (const float*)d_in[1];
  const float* bqkv = (const float*)d_in[2];
  const float* Wout = (const float*)d_in[3];
  const float* bout = (const float*)d_in[4];

  char* ws = (char*)d_ws;
  unsigned short* qkvb  = (unsigned short*)(ws);                 // 75,497,472 B
  unsigned short* Ofp   = (unsigned short*)(ws + 75497472L);     // 25,165,824 B
  unsigned short* xh    = (unsigned short*)(ws + 100663296L);    // 25,165,824 B
  unsigned short* Vt    = (unsigned short*)(ws + 100663296L);    // alias of xh
  unsigned short* WqkvT = (unsigned short*)(ws + 125829120L);    //  3,538,944 B
  unsigned short* WoutT = (unsigned short*)(ws + 129368064L);    //  1,179,648 B

  k_cvt_x<<<6144, 256, 0, stream>>>(x, xh);
  k_prep_wqkvT<<<864, 256, 0, stream>>>(Wqkv, WqkvT);
  k_prep_wout<<<288, 256, 0, stream>>>(Wout, WoutT);
  gemm128<1><<<2304, 256, 0, stream>>>(xh, WqkvT, bqkv, (void*)qkvb, 768, 2304);
  k_transposeV2<<<1536, 256, 0, stream>>>(qkvb, Vt);
  attn_fused<<<1536, 256, 0, stream>>>(qkvb, Vt, Ofp);
  gemm128<3><<<768, 256, 0, stream>>>(Ofp, WoutT, bout, d_out, 768, 768);
}

// Round 9
// 188.404 us; speedup vs baseline: 1.4640x; 1.0023x over previous
//
#include <hip/hip_runtime.h>
#include <hip/hip_bf16.h>

// Problem constants
#define B_   16
#define N_   1024
#define C_   768
#define H_   12
#define HD_  64
#define M_   16384   // B*N tokens
#define N1_  2304    // 3*C
#define NEG_BIG (-1e30f)
#define LOG2E 1.4426950408889634f

typedef __attribute__((ext_vector_type(8))) _Float16 f16x8;  // 8 fp16 = 4 VGPR
typedef __attribute__((ext_vector_type(4))) float f32x4;
typedef __attribute__((ext_vector_type(16))) float f32x16;

// ---- fp16 helpers ----
__device__ __forceinline__ unsigned short f2h(float f) {   // RNE
  _Float16 h = (_Float16)f;
  union { _Float16 h; unsigned short u; } c; c.h = h; return c.u;
}
__device__ __forceinline__ unsigned int cvtpk_f16(float a, float b) {  // RTZ pack
  unsigned int r;
  asm("v_cvt_pkrtz_f16_f32 %0, %1, %2" : "=v"(r) : "v"(a), "v"(b));
  return r;
}
__device__ __forceinline__ float exp2_asm(float x) {
  float r;
  asm("v_exp_f32 %0, %1" : "=v"(r) : "v"(x));
  return r;
}

__device__ __forceinline__ void gload_lds16(const void* g, void* l) {
  __builtin_amdgcn_global_load_lds(
      (const __attribute__((address_space(1))) void*)g,
      (__attribute__((address_space(3))) void*)l, 16, 0, 0);
}

typedef __attribute__((ext_vector_type(8))) short u16x8;

// =====================================================================
// Fused prep: blocks [0,6144) cvt x; [6144,7008) WqkvT; [7008,7296) WoutT
// =====================================================================
__global__ __launch_bounds__(256)
void k_prep_all(const float* __restrict__ x, const float* __restrict__ Wqkv,
                const float* __restrict__ Wout,
                unsigned short* __restrict__ xh,
                unsigned short* __restrict__ WqkvT,
                unsigned short* __restrict__ WoutT) {
  int bid = blockIdx.x;
  if (bid < 6144) {
    long i = ((long)bid * 256 + threadIdx.x) * 8;
    float4 a = *(const float4*)(x + i);
    float4 b = *(const float4*)(x + i + 4);
    u16x8 v;
    v[0] = (short)f2h(a.x); v[1] = (short)f2h(a.y);
    v[2] = (short)f2h(a.z); v[3] = (short)f2h(a.w);
    v[4] = (short)f2h(b.x); v[5] = (short)f2h(b.y);
    v[6] = (short)f2h(b.z); v[7] = (short)f2h(b.w);
    *(u16x8*)(xh + i) = v;
  } else if (bid < 7008) {
    int tid = (bid - 6144) * 256 + threadIdx.x;   // 96*2304 threads
    int n  = tid % N1_;
    int kc = tid / N1_;                            // 0..95
    u16x8 v;
#pragma unroll
    for (int j = 0; j < 8; ++j)
      v[j] = (short)f2h(Wqkv[(long)(kc * 8 + j) * N1_ + n]);
    *(u16x8*)(WqkvT + (long)n * C_ + kc * 8) = v;
  } else {
    int tid = (bid - 7008) * 256 + threadIdx.x;   // 96*768 threads
    int n  = tid % C_;
    int kc = tid / C_;                             // 0..95
    u16x8 v;
#pragma unroll
    for (int j = 0; j < 8; ++j)
      v[j] = (short)f2h(Wout[(long)(kc * 8 + j) * C_ + n]);
    *(u16x8*)(WoutT + (long)n * C_ + kc * 8) = v;
  }
}

// Transpose V region of qkvb into Vt [bh][64 d][1024 n] via LDS tile.
__global__ __launch_bounds__(256) void k_transposeV2(const unsigned short* __restrict__ qkvb,
                                                     unsigned short* __restrict__ Vt) {
  __shared__ unsigned char lt[16384];   // [64 d][128 n] 16-bit, swizzled
  int wid = (blockIdx.x & 7) * 192 + (blockIdx.x >> 3);   // XCD-chunked
  int bh = wid >> 3, nb = wid & 7;
  int b = bh / H_, h = bh % H_;
  long tok0 = (long)b * N_ + nb * 128;
  int t = threadIdx.x;
  int d0 = (t & 7) * 8;
#pragma unroll
  for (int it = 0; it < 4; ++it) {
    int nl = it * 32 + (t >> 3);
    u16x8 v = *(const u16x8*)(qkvb + (tok0 + nl) * N1_ + 1536 + h * HD_ + d0);
#pragma unroll
    for (int j = 0; j < 8; ++j) {
      int d = d0 + j;
      *(unsigned short*)(lt + d * 256 + ((nl * 2) ^ (((d >> 3) & 7) << 4))) =
          (unsigned short)v[j];
    }
  }
  __syncthreads();
  int l = t & 63, wv = t >> 6;
  int p = l & 1;
  int dbase = ((l >> 1) & 7) * 8 + (l >> 4) * 2;
#pragma unroll
  for (int rr = 0; rr < 4; ++rr) {
    int d = dbase + (rr & 1);
    int n0 = wv * 32 + (rr >> 1) * 16 + p * 8;
    u16x8 v = *(const u16x8*)(lt + d * 256 + ((n0 * 2) ^ (((d >> 3) & 7) << 4)));
    *(u16x8*)(Vt + ((long)bh * HD_ + d) * N_ + nb * 128 + n0) = v;
  }
}

// =====================================================================
// 128x128 GEMM (m97 2-barrier structure, fp16): C = A * Bt^T + bias
// =====================================================================
template <int STAGE>
__global__ __launch_bounds__(256, 4)
void gemm128(const unsigned short* __restrict__ A,
             const unsigned short* __restrict__ Bt,
             const float* __restrict__ bias,
             void* __restrict__ out, int Kdim, int Ndim) {
  __shared__ unsigned char lds[32768];   // A tile 16K | B tile 16K
  const int t = threadIdx.x;
  const int l = t & 63, w = t >> 6;
  const int g = l >> 4, lr = l & 15;
  const int NB = Ndim >> 7;
  const int wgid = (blockIdx.x & 7) * (gridDim.x >> 3) + (blockIdx.x >> 3);
  const int mb = wgid / NB, nb = wgid % NB;
  const long m0 = (long)mb << 7, n0 = (long)nb << 7;
  const int wm = w >> 1, wn = w & 1;

  f32x4 acc[4][4];
  const f32x4 zz = {0.f, 0.f, 0.f, 0.f};
#pragma unroll
  for (int i = 0; i < 4; ++i)
#pragma unroll
    for (int j = 0; j < 4; ++j) acc[i][j] = zz;

  int srow[4], sx[4];
#pragma unroll
  for (int i = 0; i < 4; ++i) {
    int s = i * 4096 + t * 16;
    int row = s >> 7;
    srow[i] = row;
    sx[i] = (s & 127) ^ ((row & 7) << 4);
  }
  const char* Ab = (const char*)A;
  const char* Bb = (const char*)Bt;
  const long K2 = (long)Kdim * 2;
  const int wbase = (t & 192) * 16;   // wave-uniform LDS base (w*1024)

  for (int kt = 0; kt < Kdim; kt += 64) {
#pragma unroll
    for (int i = 0; i < 4; ++i) {
      const char* src = Ab + (m0 + srow[i]) * K2 + kt * 2 + sx[i];
      gload_lds16(src, (void*)(lds + i * 4096 + wbase));
    }
#pragma unroll
    for (int i = 0; i < 4; ++i) {
      const char* src = Bb + (n0 + srow[i]) * K2 + kt * 2 + sx[i];
      gload_lds16(src, (void*)(lds + 16384 + i * 4096 + wbase));
    }
    __syncthreads();
#pragma unroll
    for (int ks = 0; ks < 2; ++ks) {
      f16x8 af[4], bfr[4];
#pragma unroll
      for (int mi = 0; mi < 4; ++mi) {
        int row = wm * 64 + mi * 16 + lr;
        int off = row * 128 + ((ks * 64 + g * 16) ^ ((row & 7) << 4));
        af[mi] = *(const f16x8*)(lds + off);
      }
#pragma unroll
      for (int ni = 0; ni < 4; ++ni) {
        int row = wn * 64 + ni * 16 + lr;
        int off = 16384 + row * 128 + ((ks * 64 + g * 16) ^ ((row & 7) << 4));
        bfr[ni] = *(const f16x8*)(lds + off);
      }
#pragma unroll
      for (int mi = 0; mi < 4; ++mi)
#pragma unroll
        for (int ni = 0; ni < 4; ++ni)
          acc[mi][ni] = __builtin_amdgcn_mfma_f32_16x16x32_f16(
              af[mi], bfr[ni], acc[mi][ni], 0, 0, 0);
    }
    __syncthreads();
  }

  // ---- epilogue ----
  if (STAGE == 1) {
    float sc = (n0 < 768) ? 0.125f * LOG2E : 1.0f;  // Q pre-scale (exp2 dom)
    unsigned short* cl = (unsigned short*)lds;
#pragma unroll
    for (int ni = 0; ni < 4; ++ni) {
      int col = wn * 64 + ni * 16 + lr;
      float bv = bias[(int)n0 + col];
#pragma unroll
      for (int mi = 0; mi < 4; ++mi)
#pragma unroll
        for (int r = 0; r < 4; ++r) {
          int row = wm * 64 + mi * 16 + g * 4 + r;
          cl[row * 128 + col] = f2h((acc[mi][ni][r] + bv) * sc);
        }
    }
    __syncthreads();
    unsigned short* o = (unsigned short*)out;
#pragma unroll
    for (int it = 0; it < 8; ++it) {
      int idx = it * 2048 + t * 8;         // shorts
      int row = idx >> 7;
      int col = idx & 127;
      *(u16x8*)(o + (m0 + row) * N1_ + n0 + col) = *(const u16x8*)(cl + idx);
    }
  } else {
    float* o = (float*)out;
#pragma unroll
    for (int ni = 0; ni < 4; ++ni) {
      int col = (int)n0 + wn * 64 + ni * 16 + lr;
      float bv = bias[col];
#pragma unroll
      for (int mi = 0; mi < 4; ++mi)
#pragma unroll
        for (int r = 0; r < 4; ++r) {
          long rowm = m0 + wm * 64 + mi * 16 + g * 4 + r;
          o[rowm * C_ + col] = acc[mi][ni][r] + bv;
        }
    }
  }
}

// =====================================================================
// Fused flash attention, 32x32x16 fp16 MFMA, fully-transposed form.
// Online softmax with defer-max (bounds exp2 input: P <= 2^8, no fp16
// saturation). Row-sum via ones-MFMA (matrix pipe) replaces VALU tree;
// on rescale only osum[0] is scaled (elementwise MFMA accumulation).
// =====================================================================
__global__ __launch_bounds__(256, 4)
void attn_fused(const unsigned short* __restrict__ qkvb,
                const unsigned short* __restrict__ Vt,
                unsigned short* __restrict__ Ofp) {
  __shared__ unsigned char lds[32768];  // 2 x (K 8K | V 8K)
  const int t = threadIdx.x, l = t & 63, w = t >> 6;
  const int q32 = l & 31;
  const int hi = l >> 5;
  const int hi16 = hi * 16;
  const int wid = (blockIdx.x & 7) * 192 + (blockIdx.x >> 3);
  const int bh = wid >> 3, qb = wid & 7;
  const int b = bh / H_, h = bh % H_;
  const long tok0 = (long)b * N_;
  const int q0 = qb * 128 + w * 32;
  const long mytok = tok0 + q0 + q32;

  // Q B-fragments (pre-scaled by 0.125*log2e in stage-1)
  f16x8 qa[4];
#pragma unroll
  for (int cs = 0; cs < 4; ++cs)
    qa[cs] = *(const f16x8*)(qkvb + mytok * N1_ + h * HD_ + cs * 16 + hi * 8);

  const f32x16 zz16 = {0.f};
  f32x16 o0 = zz16, o1 = zz16;   // O^T: d 0..31 / 32..63 for lane's q
  f32x16 osum = zz16;            // row-sum accumulator (ones-MFMA)
  float mrun = NEG_BIG;
  f16x8 ones;
#pragma unroll
  for (int i = 0; i < 8; ++i) ones[i] = (_Float16)1.0f;

  const int row0 = q32, row1 = 32 + q32;
  const int swz0 = (q32 & 7) << 4;    // period-8 / 16B XOR

  const int sxs = ((t & 7) * 16) ^ (((t >> 3) & 7) << 4);
  const int wbase = (t & 192) * 16;
  const char* Vg = (const char*)(Vt + (long)bh * HD_ * N_);
  const char* Kg = (const char*)qkvb + ((tok0)*N1_ + C_ + h * HD_) * 2;

#define STAGE_KV(kv0, buf)                                                  \
  {                                                                         \
    _Pragma("unroll")                                                       \
    for (int i = 0; i < 2; ++i) {                                           \
      int row = i * 32 + (t >> 3);                                          \
      gload_lds16(Kg + ((long)(kv0 + row) * N1_) * 2 + sxs,                 \
                  (void*)((buf) + i * 4096 + wbase));                       \
    }                                                                       \
    _Pragma("unroll")                                                       \
    for (int i = 0; i < 2; ++i) {                                           \
      int row = i * 32 + (t >> 3);                                          \
      gload_lds16(Vg + ((long)row * N_ + (kv0)) * 2 + sxs,                  \
                  (void*)((buf) + 8192 + i * 4096 + wbase));                \
    }                                                                       \
  }

  STAGE_KV(0, lds);

#pragma unroll 2
  for (int tt = 0; tt < 16; ++tt) {
    unsigned char* curb = lds + (tt & 1) * 16384;
    unsigned char* nxtb = lds + ((tt & 1) ^ 1) * 16384;
    if (tt < 15) {
      STAGE_KV((tt + 1) * 64, nxtb);
      asm volatile("s_waitcnt vmcnt(4)" ::: "memory");
    } else {
      asm volatile("s_waitcnt vmcnt(0)" ::: "memory");
    }
    __builtin_amdgcn_s_barrier();
    __builtin_amdgcn_sched_barrier(0);

    // ---- S^T = mfma(K_A, Q_B) ----
    f32x16 sa0 = zz16, sa1 = zz16;
#pragma unroll
    for (int cs = 0; cs < 4; ++cs) {
      f16x8 kf0 = *(const f16x8*)(curb + row0 * 128 + ((cs * 32 + hi16) ^ swz0));
      f16x8 kf1 = *(const f16x8*)(curb + row1 * 128 + ((cs * 32 + hi16) ^ swz0));
      sa0 = __builtin_amdgcn_mfma_f32_32x32x16_f16(kf0, qa[cs], sa0, 0, 0, 0);
      sa1 = __builtin_amdgcn_mfma_f32_32x32x16_f16(kf1, qa[cs], sa1, 0, 0, 0);
    }

    // ---- in-lane online softmax (log2 domain), max3-fused tree ----
    float tm[11];
#pragma unroll
    for (int i = 0; i < 5; ++i)
      tm[i] = fmaxf(fmaxf(sa0[3 * i], sa0[3 * i + 1]), sa0[3 * i + 2]);
    tm[5] = fmaxf(sa0[15], sa1[0]);
#pragma unroll
    for (int i = 0; i < 5; ++i)
      tm[6 + i] = fmaxf(fmaxf(sa1[3 * i + 1], sa1[3 * i + 2]), sa1[3 * i + 3]);
    float u0 = fmaxf(fmaxf(tm[0], tm[1]), tm[2]);
    float u1 = fmaxf(fmaxf(tm[3], tm[4]), tm[5]);
    float u2 = fmaxf(fmaxf(tm[6], tm[7]), tm[8]);
    float u3 = fmaxf(fmaxf(tm[9], tm[10]), u0);
    float mx = fmaxf(fmaxf(u1, u2), u3);
    mx = fmaxf(mx, __shfl_xor(mx, 32));
    if (!__all(mx <= mrun + 8.f)) {           // defer-max: P <= 2^8
      float mn = fmaxf(mrun, mx);
      float al = exp2_asm(mrun - mn);
      mrun = mn;
      o0 *= al;
      o1 *= al;
      osum[0] *= al;                          // only element we ever read
    }
    float p0a[16], p1a[16];
#pragma unroll
    for (int i = 0; i < 16; ++i) p0a[i] = exp2_asm(sa0[i] - mrun);
#pragma unroll
    for (int i = 0; i < 16; ++i) p1a[i] = exp2_asm(sa1[i] - mrun);
    unsigned pk[2][4][2];
#pragma unroll
    for (int g = 0; g < 4; ++g) {
      pk[0][g][0] = cvtpk_f16(p0a[4 * g + 0], p0a[4 * g + 1]);
      pk[0][g][1] = cvtpk_f16(p0a[4 * g + 2], p0a[4 * g + 3]);
      pk[1][g][0] = cvtpk_f16(p1a[4 * g + 0], p1a[4 * g + 1]);
      pk[1][g][1] = cvtpk_f16(p1a[4 * g + 2], p1a[4 * g + 3]);
    }

    // ---- P^T -> B-operand fragments via permlane32_swap ----
    f16x8 pb[4];
#pragma unroll
    for (int tk = 0; tk < 2; ++tk)
#pragma unroll
      for (int par = 0; par < 2; ++par) {
        unsigned a0 = pk[tk][2 * par][0], b0 = pk[tk][2 * par + 1][0];
        unsigned a1 = pk[tk][2 * par][1], b1 = pk[tk][2 * par + 1][1];
        asm("v_permlane32_swap_b32 %0, %1" : "+v"(a0), "+v"(b0));
        asm("v_permlane32_swap_b32 %0, %1" : "+v"(a1), "+v"(b1));
        union { unsigned u[4]; f16x8 v; } pw;
        pw.u[0] = a0; pw.u[1] = a1; pw.u[2] = b0; pw.u[3] = b1;
        pb[2 * tk + par] = pw.v;
      }

    // ---- O^T += mfma(V^T_A, P_B); row-sum += mfma(ones, P_B) ----
#pragma unroll
    for (int kb = 0; kb < 4; ++kb) {
      f16x8 vf0 = *(const f16x8*)(curb + 8192 + row0 * 128 + ((kb * 32 + hi16) ^ swz0));
      f16x8 vf1 = *(const f16x8*)(curb + 8192 + row1 * 128 + ((kb * 32 + hi16) ^ swz0));
      o0 = __builtin_amdgcn_mfma_f32_32x32x16_f16(vf0, pb[kb], o0, 0, 0, 0);
      o1 = __builtin_amdgcn_mfma_f32_32x32x16_f16(vf1, pb[kb], o1, 0, 0, 0);
      osum = __builtin_amdgcn_mfma_f32_32x32x16_f16(ones, pb[kb], osum, 0, 0, 0);
    }
    __builtin_amdgcn_sched_barrier(0);
    asm volatile("s_waitcnt lgkmcnt(0)" ::: "memory");
    __builtin_amdgcn_s_barrier();
  }
#undef STAGE_KV

  // ---- epilogue: normalize by MFMA row-sum, fp16 pack, dword stores ----
  float inv = 1.0f / osum[0];
  unsigned short* obase = Ofp + mytok * C_ + h * HD_;
#pragma unroll
  for (int dt = 0; dt < 2; ++dt) {
#pragma unroll
    for (int rp = 0; rp < 8; ++rp) {
      int r = rp * 2;
      float v0 = (dt ? o1[r] : o0[r]) * inv;
      float v1 = (dt ? o1[r + 1] : o0[r + 1]) * inv;
      unsigned hw = cvtpk_f16(v0, v1);
      int d = dt * 32 + (r & 3) + 8 * (r >> 2) + 4 * hi;
      *(unsigned*)(obase + d) = hw;
    }
  }
}

// =====================================================================
extern "C" void kernel_launch(void* const* d_in, const int* in_sizes, int n_in,
                              void* d_out, int out_size, void* d_ws, size_t ws_size,
                              hipStream_t stream) {
  const float* x    = (const float*)d_in[0];
  const float* Wqkv = (const float*)d_in[1];
  const float* bqkv = (const float*)d_in[2];
  const float* Wout = (const float*)d_in[3];
  const float* bout = (const float*)d_in[4];

  char* ws = (char*)d_ws;
  unsigned short* qkvb  = (unsigned short*)(ws);                 // 75,497,472 B
  unsigned short* Ofp   = (unsigned short*)(ws + 75497472L);     // 25,165,824 B
  unsigned short* xh    = (unsigned short*)(ws + 100663296L);    // 25,165,824 B
  unsigned short* Vt    = (unsigned short*)(ws + 100663296L);    // alias of xh
  unsigned short* WqkvT = (unsigned short*)(ws + 125829120L);    //  3,538,944 B
  unsigned short* WoutT = (unsigned short*)(ws + 129368064L);    //  1,179,648 B

  k_prep_all<<<7296, 256, 0, stream>>>(x, Wqkv, Wout, xh, WqkvT, WoutT);
  gemm128<1><<<2304, 256, 0, stream>>>(xh, WqkvT, bqkv, (void*)qkvb, 768, 2304);
  k_transposeV2<<<1536, 256, 0, stream>>>(qkvb, Vt);
  attn_fused<<<1536, 256, 0, stream>>>(qkvb, Vt, Ofp);
  gemm128<3><<<768, 256, 0, stream>>>(Ofp, WoutT, bout, d_out, 768, 768);
}

// Round 10
// 177.918 us; speedup vs baseline: 1.5503x; 1.0589x over previous
//
#include <hip/hip_runtime.h>
#include <hip/hip_bf16.h>

// Problem constants
#define B_   16
#define N_   1024
#define C_   768
#define H_   12
#define HD_  64
#define M_   16384   // B*N tokens
#define N1_  2304    // 3*C
#define NEG_BIG (-1e30f)
#define LOG2E 1.4426950408889634f

typedef __attribute__((ext_vector_type(8))) _Float16 f16x8;  // 8 fp16 = 4 VGPR
typedef __attribute__((ext_vector_type(4))) float f32x4;
typedef __attribute__((ext_vector_type(16))) float f32x16;

// ---- fp16 helpers ----
__device__ __forceinline__ unsigned short f2h(float f) {   // RNE
  _Float16 h = (_Float16)f;
  union { _Float16 h; unsigned short u; } c; c.h = h; return c.u;
}
__device__ __forceinline__ unsigned int cvtpk_f16(float a, float b) {  // RTZ pack
  unsigned int r;
  asm("v_cvt_pkrtz_f16_f32 %0, %1, %2" : "=v"(r) : "v"(a), "v"(b));
  return r;
}
__device__ __forceinline__ float exp2_asm(float x) {
  float r;
  asm("v_exp_f32 %0, %1" : "=v"(r) : "v"(x));
  return r;
}

__device__ __forceinline__ void gload_lds16(const void* g, void* l) {
  __builtin_amdgcn_global_load_lds(
      (const __attribute__((address_space(1))) void*)g,
      (__attribute__((address_space(3))) void*)l, 16, 0, 0);
}

typedef __attribute__((ext_vector_type(8))) short u16x8;

// =====================================================================
// Fused prep: blocks [0,6144) cvt x; [6144,7008) WqkvT; [7008,7296) WoutT
// =====================================================================
__global__ __launch_bounds__(256)
void k_prep_all(const float* __restrict__ x, const float* __restrict__ Wqkv,
                const float* __restrict__ Wout,
                unsigned short* __restrict__ xh,
                unsigned short* __restrict__ WqkvT,
                unsigned short* __restrict__ WoutT) {
  int bid = blockIdx.x;
  if (bid < 6144) {
    long i = ((long)bid * 256 + threadIdx.x) * 8;
    float4 a = *(const float4*)(x + i);
    float4 b = *(const float4*)(x + i + 4);
    u16x8 v;
    v[0] = (short)f2h(a.x); v[1] = (short)f2h(a.y);
    v[2] = (short)f2h(a.z); v[3] = (short)f2h(a.w);
    v[4] = (short)f2h(b.x); v[5] = (short)f2h(b.y);
    v[6] = (short)f2h(b.z); v[7] = (short)f2h(b.w);
    *(u16x8*)(xh + i) = v;
  } else if (bid < 7008) {
    int tid = (bid - 6144) * 256 + threadIdx.x;   // 96*2304 threads
    int n  = tid % N1_;
    int kc = tid / N1_;                            // 0..95
    u16x8 v;
#pragma unroll
    for (int j = 0; j < 8; ++j)
      v[j] = (short)f2h(Wqkv[(long)(kc * 8 + j) * N1_ + n]);
    *(u16x8*)(WqkvT + (long)n * C_ + kc * 8) = v;
  } else {
    int tid = (bid - 7008) * 256 + threadIdx.x;   // 96*768 threads
    int n  = tid % C_;
    int kc = tid / C_;                             // 0..95
    u16x8 v;
#pragma unroll
    for (int j = 0; j < 8; ++j)
      v[j] = (short)f2h(Wout[(long)(kc * 8 + j) * C_ + n]);
    *(u16x8*)(WoutT + (long)n * C_ + kc * 8) = v;
  }
}

// =====================================================================
// 128x128 GEMM (m97 2-barrier structure, fp16): C = A * Bt^T + bias
// STAGE 1: fp16 out. Q/K col-blocks -> qkvb (LDS-coalesced rows).
//          V col-blocks (n0>=1536) -> transposed directly into
//          Vt [bh][64 d][1024 n] via col-major swizzled LDS tile
//          (k_transposeV2 eliminated; qkvb V-region never written).
// STAGE 3: fp32 direct.
// =====================================================================
template <int STAGE>
__global__ __launch_bounds__(256, 4)
void gemm128(const unsigned short* __restrict__ A,
             const unsigned short* __restrict__ Bt,
             const float* __restrict__ bias,
             void* __restrict__ out, unsigned short* __restrict__ Vt,
             int Kdim, int Ndim) {
  __shared__ unsigned char lds[32768];   // A tile 16K | B tile 16K
  const int t = threadIdx.x;
  const int l = t & 63, w = t >> 6;
  const int g = l >> 4, lr = l & 15;
  const int NB = Ndim >> 7;
  const int wgid = (blockIdx.x & 7) * (gridDim.x >> 3) + (blockIdx.x >> 3);
  const int mb = wgid / NB, nb = wgid % NB;
  const long m0 = (long)mb << 7, n0 = (long)nb << 7;
  const int wm = w >> 1, wn = w & 1;

  f32x4 acc[4][4];
  const f32x4 zz = {0.f, 0.f, 0.f, 0.f};
#pragma unroll
  for (int i = 0; i < 4; ++i)
#pragma unroll
    for (int j = 0; j < 4; ++j) acc[i][j] = zz;

  int srow[4], sx[4];
#pragma unroll
  for (int i = 0; i < 4; ++i) {
    int s = i * 4096 + t * 16;
    int row = s >> 7;
    srow[i] = row;
    sx[i] = (s & 127) ^ ((row & 7) << 4);
  }
  const char* Ab = (const char*)A;
  const char* Bb = (const char*)Bt;
  const long K2 = (long)Kdim * 2;
  const int wbase = (t & 192) * 16;   // wave-uniform LDS base (w*1024)

  for (int kt = 0; kt < Kdim; kt += 64) {
#pragma unroll
    for (int i = 0; i < 4; ++i) {
      const char* src = Ab + (m0 + srow[i]) * K2 + kt * 2 + sx[i];
      gload_lds16(src, (void*)(lds + i * 4096 + wbase));
    }
#pragma unroll
    for (int i = 0; i < 4; ++i) {
      const char* src = Bb + (n0 + srow[i]) * K2 + kt * 2 + sx[i];
      gload_lds16(src, (void*)(lds + 16384 + i * 4096 + wbase));
    }
    __syncthreads();
#pragma unroll
    for (int ks = 0; ks < 2; ++ks) {
      f16x8 af[4], bfr[4];
#pragma unroll
      for (int mi = 0; mi < 4; ++mi) {
        int row = wm * 64 + mi * 16 + lr;
        int off = row * 128 + ((ks * 64 + g * 16) ^ ((row & 7) << 4));
        af[mi] = *(const f16x8*)(lds + off);
      }
#pragma unroll
      for (int ni = 0; ni < 4; ++ni) {
        int row = wn * 64 + ni * 16 + lr;
        int off = 16384 + row * 128 + ((ks * 64 + g * 16) ^ ((row & 7) << 4));
        bfr[ni] = *(const f16x8*)(lds + off);
      }
#pragma unroll
      for (int mi = 0; mi < 4; ++mi)
#pragma unroll
        for (int ni = 0; ni < 4; ++ni)
          acc[mi][ni] = __builtin_amdgcn_mfma_f32_16x16x32_f16(
              af[mi], bfr[ni], acc[mi][ni], 0, 0, 0);
    }
    __syncthreads();
  }

  // ---- epilogue ----
  if (STAGE == 1 && n0 >= 1536) {
    // V path: stage C-tile COL-MAJOR (lt[col][row^s]) then write Vt rows
    unsigned short* lt = (unsigned short*)lds;
#pragma unroll
    for (int ni = 0; ni < 4; ++ni) {
      int col = wn * 64 + ni * 16 + lr;
      int s = (col & 15) << 3;
      float bv = bias[(int)n0 + col];
#pragma unroll
      for (int mi = 0; mi < 4; ++mi) {
        int rowb = wm * 64 + mi * 16 + g * 4;
        unsigned d0 = cvtpk_f16(acc[mi][ni][0] + bv, acc[mi][ni][1] + bv);
        unsigned d1 = cvtpk_f16(acc[mi][ni][2] + bv, acc[mi][ni][3] + bv);
        unsigned long long dd = (unsigned long long)d0 |
                                ((unsigned long long)d1 << 32);
        *(unsigned long long*)(lt + col * 128 + (rowb ^ s)) = dd;
      }
    }
    __syncthreads();
    const int b_  = (int)(m0 >> 10);
    const int nof = (int)(m0 & 1023);
    const int h0  = ((int)n0 - 1536) >> 6;
#pragma unroll
    for (int it = 0; it < 8; ++it) {
      int col  = it * 16 + (t >> 4);
      int tokc = (t & 15) * 8;
      int s = (col & 15) << 3;
      u16x8 v = *(const u16x8*)(lt + col * 128 + (tokc ^ s));
      int bh = b_ * H_ + h0 + (col >> 6);
      int d  = col & 63;
      *(u16x8*)(Vt + ((long)bh * HD_ + d) * N_ + nof + tokc) = v;
    }
  } else if (STAGE == 1) {
    float sc = (n0 < 768) ? 0.125f * LOG2E : 1.0f;  // Q pre-scale (exp2 dom)
    unsigned short* cl = (unsigned short*)lds;
#pragma unroll
    for (int ni = 0; ni < 4; ++ni) {
      int col = wn * 64 + ni * 16 + lr;
      float bv = bias[(int)n0 + col];
#pragma unroll
      for (int mi = 0; mi < 4; ++mi)
#pragma unroll
        for (int r = 0; r < 4; ++r) {
          int row = wm * 64 + mi * 16 + g * 4 + r;
          cl[row * 128 + col] = f2h((acc[mi][ni][r] + bv) * sc);
        }
    }
    __syncthreads();
    unsigned short* o = (unsigned short*)out;
#pragma unroll
    for (int it = 0; it < 8; ++it) {
      int idx = it * 2048 + t * 8;         // shorts
      int row = idx >> 7;
      int col = idx & 127;
      *(u16x8*)(o + (m0 + row) * N1_ + n0 + col) = *(const u16x8*)(cl + idx);
    }
  } else {
    float* o = (float*)out;
#pragma unroll
    for (int ni = 0; ni < 4; ++ni) {
      int col = (int)n0 + wn * 64 + ni * 16 + lr;
      float bv = bias[col];
#pragma unroll
      for (int mi = 0; mi < 4; ++mi)
#pragma unroll
        for (int r = 0; r < 4; ++r) {
          long rowm = m0 + wm * 64 + mi * 16 + g * 4 + r;
          o[rowm * C_ + col] = acc[mi][ni][r] + bv;
        }
    }
  }
}

// =====================================================================
// Fused flash attention, 32x32x16 fp16 MFMA, fully-transposed form.
// Online softmax with defer-max; VALU sum tree (r7 structure — the
// ones-MFMA variant measured slower). Merged 8B epilogue stores.
// =====================================================================
__global__ __launch_bounds__(256, 4)
void attn_fused(const unsigned short* __restrict__ qkvb,
                const unsigned short* __restrict__ Vt,
                unsigned short* __restrict__ Ofp) {
  __shared__ unsigned char lds[32768];  // 2 x (K 8K | V 8K)
  const int t = threadIdx.x, l = t & 63, w = t >> 6;
  const int q32 = l & 31;
  const int hi = l >> 5;
  const int hi16 = hi * 16;
  const int wid = (blockIdx.x & 7) * 192 + (blockIdx.x >> 3);
  const int bh = wid >> 3, qb = wid & 7;
  const int b = bh / H_, h = bh % H_;
  const long tok0 = (long)b * N_;
  const int q0 = qb * 128 + w * 32;
  const long mytok = tok0 + q0 + q32;

  // Q B-fragments (pre-scaled by 0.125*log2e in stage-1)
  f16x8 qa[4];
#pragma unroll
  for (int cs = 0; cs < 4; ++cs)
    qa[cs] = *(const f16x8*)(qkvb + mytok * N1_ + h * HD_ + cs * 16 + hi * 8);

  const f32x16 zz16 = {0.f};
  f32x16 o0 = zz16, o1 = zz16;   // O^T: d 0..31 / 32..63 for lane's q
  float mrun = NEG_BIG, lrun = 0.f;

  const int row0 = q32, row1 = 32 + q32;
  const int swz0 = (q32 & 7) << 4;    // period-8 / 16B XOR

  const int sxs = ((t & 7) * 16) ^ (((t >> 3) & 7) << 4);
  const int wbase = (t & 192) * 16;
  const char* Vg = (const char*)(Vt + (long)bh * HD_ * N_);
  const char* Kg = (const char*)qkvb + ((tok0)*N1_ + C_ + h * HD_) * 2;

#define STAGE_KV(kv0, buf)                                                  \
  {                                                                         \
    _Pragma("unroll")                                                       \
    for (int i = 0; i < 2; ++i) {                                           \
      int row = i * 32 + (t >> 3);                                          \
      gload_lds16(Kg + ((long)(kv0 + row) * N1_) * 2 + sxs,                 \
                  (void*)((buf) + i * 4096 + wbase));                       \
    }                                                                       \
    _Pragma("unroll")                                                       \
    for (int i = 0; i < 2; ++i) {                                           \
      int row = i * 32 + (t >> 3);                                          \
      gload_lds16(Vg + ((long)row * N_ + (kv0)) * 2 + sxs,                  \
                  (void*)((buf) + 8192 + i * 4096 + wbase));                \
    }                                                                       \
  }

  STAGE_KV(0, lds);

#pragma unroll 2
  for (int tt = 0; tt < 16; ++tt) {
    unsigned char* curb = lds + (tt & 1) * 16384;
    unsigned char* nxtb = lds + ((tt & 1) ^ 1) * 16384;
    if (tt < 15) {
      STAGE_KV((tt + 1) * 64, nxtb);
      asm volatile("s_waitcnt vmcnt(4)" ::: "memory");
    } else {
      asm volatile("s_waitcnt vmcnt(0)" ::: "memory");
    }
    __builtin_amdgcn_s_barrier();
    __builtin_amdgcn_sched_barrier(0);

    // ---- S^T = mfma(K_A, Q_B) ----
    f32x16 sa0 = zz16, sa1 = zz16;
#pragma unroll
    for (int cs = 0; cs < 4; ++cs) {
      f16x8 kf0 = *(const f16x8*)(curb + row0 * 128 + ((cs * 32 + hi16) ^ swz0));
      f16x8 kf1 = *(const f16x8*)(curb + row1 * 128 + ((cs * 32 + hi16) ^ swz0));
      sa0 = __builtin_amdgcn_mfma_f32_32x32x16_f16(kf0, qa[cs], sa0, 0, 0, 0);
      sa1 = __builtin_amdgcn_mfma_f32_32x32x16_f16(kf1, qa[cs], sa1, 0, 0, 0);
    }

    // ---- in-lane online softmax (log2 domain), max3-fused tree ----
    float tm[11];
#pragma unroll
    for (int i = 0; i < 5; ++i)
      tm[i] = fmaxf(fmaxf(sa0[3 * i], sa0[3 * i + 1]), sa0[3 * i + 2]);
    tm[5] = fmaxf(sa0[15], sa1[0]);
#pragma unroll
    for (int i = 0; i < 5; ++i)
      tm[6 + i] = fmaxf(fmaxf(sa1[3 * i + 1], sa1[3 * i + 2]), sa1[3 * i + 3]);
    float u0 = fmaxf(fmaxf(tm[0], tm[1]), tm[2]);
    float u1 = fmaxf(fmaxf(tm[3], tm[4]), tm[5]);
    float u2 = fmaxf(fmaxf(tm[6], tm[7]), tm[8]);
    float u3 = fmaxf(fmaxf(tm[9], tm[10]), u0);
    float mx = fmaxf(fmaxf(u1, u2), u3);
    mx = fmaxf(mx, __shfl_xor(mx, 32));
    if (!__all(mx <= mrun + 8.f)) {           // defer-max: P <= 2^8
      float mn = fmaxf(mrun, mx);
      float al = exp2_asm(mrun - mn);
      mrun = mn;
      lrun *= al;
      o0 *= al;
      o1 *= al;
    }
    float p0a[16], p1a[16];
#pragma unroll
    for (int i = 0; i < 16; ++i) p0a[i] = exp2_asm(sa0[i] - mrun);
#pragma unroll
    for (int i = 0; i < 16; ++i) p1a[i] = exp2_asm(sa1[i] - mrun);
    unsigned pk[2][4][2];
#pragma unroll
    for (int g = 0; g < 4; ++g) {
      pk[0][g][0] = cvtpk_f16(p0a[4 * g + 0], p0a[4 * g + 1]);
      pk[0][g][1] = cvtpk_f16(p0a[4 * g + 2], p0a[4 * g + 3]);
      pk[1][g][0] = cvtpk_f16(p1a[4 * g + 0], p1a[4 * g + 1]);
      pk[1][g][1] = cvtpk_f16(p1a[4 * g + 2], p1a[4 * g + 3]);
    }
    float ts[16];
#pragma unroll
    for (int i = 0; i < 16; ++i) ts[i] = p0a[i] + p1a[i];
#pragma unroll
    for (int s = 8; s >= 1; s >>= 1)
#pragma unroll
      for (int i = 0; i < s; ++i) ts[i] += ts[i + s];
    float rs = ts[0];
    rs += __shfl_xor(rs, 32);
    lrun += rs;

    // ---- P^T -> B-operand fragments via permlane32_swap ----
    f16x8 pb[4];
#pragma unroll
    for (int tk = 0; tk < 2; ++tk)
#pragma unroll
      for (int par = 0; par < 2; ++par) {
        unsigned a0 = pk[tk][2 * par][0], b0 = pk[tk][2 * par + 1][0];
        unsigned a1 = pk[tk][2 * par][1], b1 = pk[tk][2 * par + 1][1];
        asm("v_permlane32_swap_b32 %0, %1" : "+v"(a0), "+v"(b0));
        asm("v_permlane32_swap_b32 %0, %1" : "+v"(a1), "+v"(b1));
        union { unsigned u[4]; f16x8 v; } pw;
        pw.u[0] = a0; pw.u[1] = a1; pw.u[2] = b0; pw.u[3] = b1;
        pb[2 * tk + par] = pw.v;
      }

    // ---- O^T += mfma(V^T_A, P_B) ----
#pragma unroll
    for (int kb = 0; kb < 4; ++kb) {
      f16x8 vf0 = *(const f16x8*)(curb + 8192 + row0 * 128 + ((kb * 32 + hi16) ^ swz0));
      f16x8 vf1 = *(const f16x8*)(curb + 8192 + row1 * 128 + ((kb * 32 + hi16) ^ swz0));
      o0 = __builtin_amdgcn_mfma_f32_32x32x16_f16(vf0, pb[kb], o0, 0, 0, 0);
      o1 = __builtin_amdgcn_mfma_f32_32x32x16_f16(vf1, pb[kb], o1, 0, 0, 0);
    }
    __builtin_amdgcn_sched_barrier(0);
    asm volatile("s_waitcnt lgkmcnt(0)" ::: "memory");
    __builtin_amdgcn_s_barrier();
  }
#undef STAGE_KV

  // ---- epilogue: normalize, fp16 pack, merged 8B stores ----
  float inv = 1.0f / lrun;
  unsigned short* obase = Ofp + mytok * C_ + h * HD_;
#pragma unroll
  for (int dt = 0; dt < 2; ++dt) {
#pragma unroll
    for (int j = 0; j < 4; ++j) {
      int r = 4 * j;
      const f32x16& oo = dt ? o1 : o0;
      unsigned hw0 = cvtpk_f16(oo[r] * inv, oo[r + 1] * inv);
      unsigned hw1 = cvtpk_f16(oo[r + 2] * inv, oo[r + 3] * inv);
      unsigned long long dd = (unsigned long long)hw0 |
                              ((unsigned long long)hw1 << 32);
      int d = dt * 32 + 8 * j + 4 * hi;
      *(unsigned long long*)(obase + d) = dd;
    }
  }
}

// =====================================================================
extern "C" void kernel_launch(void* const* d_in, const int* in_sizes, int n_in,
                              void* d_out, int out_size, void* d_ws, size_t ws_size,
                              hipStream_t stream) {
  const float* x    = (const float*)d_in[0];
  const float* Wqkv = (const float*)d_in[1];
  const float* bqkv = (const float*)d_in[2];
  const float* Wout = (const float*)d_in[3];
  const float* bout = (const float*)d_in[4];

  char* ws = (char*)d_ws;
  unsigned short* qkvb  = (unsigned short*)(ws);                 // 75,497,472 B
  unsigned short* Ofp   = (unsigned short*)(ws + 75497472L);     // 25,165,824 B
  unsigned short* xh    = (unsigned short*)(ws + 100663296L);    // 25,165,824 B
  unsigned short* Vt    = (unsigned short*)(ws + 125829120L);    // 25,165,824 B (own region; gemm1 reads xh)
  unsigned short* WqkvT = (unsigned short*)(ws + 150994944L);    //  3,538,944 B
  unsigned short* WoutT = (unsigned short*)(ws + 154533888L);    //  1,179,648 B
  // total: 155,713,536 B

  k_prep_all<<<7296, 256, 0, stream>>>(x, Wqkv, Wout, xh, WqkvT, WoutT);
  gemm128<1><<<2304, 256, 0, stream>>>(xh, WqkvT, bqkv, (void*)qkvb, Vt, 768, 2304);
  attn_fused<<<1536, 256, 0, stream>>>(qkvb, Vt, Ofp);
  gemm128<3><<<768, 256, 0, stream>>>(Ofp, WoutT, bout, d_out, nullptr, 768, 768);
}